// Round 5
// baseline (19153.169 us; speedup 1.0000x reference)
//
#include <hip/hip_runtime.h>
#include <math.h>

#define HID 512
#define BAT 512
#define NIN 128
#define TST 128
#define HOR 32
#define SBZ ((size_t)BAT * HID)

using bf16x8 = __attribute__((ext_vector_type(8))) __bf16;
using f32x4  = __attribute__((ext_vector_type(4))) float;

__device__ __forceinline__ float sigf(float x) { return 1.0f / (1.0f + expf(-x)); }

__device__ __forceinline__ short f2bf(float x) {
    union { float f; unsigned u; } v; v.f = x;
    unsigned r = (v.u + 0x7FFFu + ((v.u >> 16) & 1u)) >> 16;
    return (short)r;
}
__device__ __forceinline__ float bf2f(short s) {
    union { unsigned u; float f; } v; v.u = ((unsigned)(unsigned short)s) << 16;
    return v.f;
}
__device__ __forceinline__ void async16(const void* g, void* l) {
    __builtin_amdgcn_global_load_lds(
        (const __attribute__((address_space(1))) void*)g,
        (__attribute__((address_space(3))) void*)l, 16, 0, 0);
}

// device-scope grid barrier: monotone counter, release-add / acquire-spin
__device__ __forceinline__ void gbar(unsigned* cnt, unsigned target) {
    __syncthreads();
    if (threadIdx.x == 0) {
        __hip_atomic_fetch_add(cnt, 1u, __ATOMIC_RELEASE, __HIP_MEMORY_SCOPE_AGENT);
        while (__hip_atomic_load(cnt, __ATOMIC_ACQUIRE, __HIP_MEMORY_SCOPE_AGENT) < target)
            __builtin_amdgcn_s_sleep(8);
    }
    __syncthreads();
}

// ---------------- prep kernels ----------------

// permuted weight rows: n' = u*4 + gate  <->  orig row gate*512 + u
// cols: [0,Kx)=Wih_hi [Kx,2Kx)=Wih_lo [2Kx,2Kx+512)=Whh_hi [2Kx+512,Kp)=Whh_lo
__global__ __launch_bounds__(256) void prep_w(const float* __restrict__ Wih,
                                              const float* __restrict__ Whh,
                                              short* __restrict__ W2, int Kx, int Kp) {
    size_t i = (size_t)blockIdx.x * 256 + threadIdx.x;
    if (i >= (size_t)2048 * Kp) return;
    int np = (int)(i / Kp), kp = (int)(i % Kp);
    int u = np >> 2, gate = np & 3;
    int on = gate * HID + u;
    float w; bool islo = false;
    if (kp < Kx)                { w = Wih[(size_t)on * Kx + kp]; }
    else if (kp < 2 * Kx)       { w = Wih[(size_t)on * Kx + (kp - Kx)]; islo = true; }
    else if (kp < 2 * Kx + HID) { w = Whh[(size_t)on * HID + (kp - 2 * Kx)]; }
    else                        { w = Whh[(size_t)on * HID + (kp - 2 * Kx - HID)]; islo = true; }
    short hi = f2bf(w);
    W2[i] = islo ? f2bf(w - bf2f(hi)) : hi;
}

__global__ __launch_bounds__(256) void prep_x(const float* __restrict__ window,
                                              short* __restrict__ x2) {
    size_t i = (size_t)blockIdx.x * 256 + threadIdx.x;
    if (i >= (size_t)TST * BAT * NIN) return;
    int n = (int)(i & 127);
    int b = (int)((i >> 7) & 511);
    int t = (int)(i >> 16);
    float x = window[(size_t)b * (TST * NIN) + (size_t)t * NIN + n];
    short hi = f2bf(x);
    short* dst = x2 + (size_t)t * (BAT * 256) + (size_t)b * 256;
    dst[n] = hi;
    dst[128 + n] = f2bf(x - bf2f(hi));
}

__global__ __launch_bounds__(256) void prep_fuse(const float* __restrict__ Wc1i,
                                                 const float* __restrict__ Wp,
                                                 float* __restrict__ Wfuse) {
    size_t i = (size_t)blockIdx.x * 256 + threadIdx.x;
    if (i >= (size_t)2048 * 512) return;
    int on = (int)(i >> 9), k = (int)(i & 511);
    float s = 0.f;
    for (int n = 0; n < NIN; ++n) s += Wc1i[(size_t)on * NIN + n] * Wp[(size_t)n * HID + k];
    Wfuse[i] = s;
}

__global__ __launch_bounds__(256) void prep_badd(const float* __restrict__ Wc1i,
                                                 const float* __restrict__ bp,
                                                 float* __restrict__ badd) {
    int on = blockIdx.x * 256 + threadIdx.x;
    if (on >= 2048) return;
    float s = 0.f;
    for (int n = 0; n < NIN; ++n) s += Wc1i[(size_t)on * NIN + n] * bp[n];
    badd[on] = s;
}

// bias_p[n'] = bih[on]+bhh[on](+badd[on]), n' = u*4+gate
__global__ __launch_bounds__(256) void prep_bias(const float* __restrict__ bih,
                                                 const float* __restrict__ bhh,
                                                 const float* __restrict__ badd,
                                                 float* __restrict__ bout) {
    int np = blockIdx.x * 256 + threadIdx.x;
    if (np >= 2048) return;
    int on = (np & 3) * HID + (np >> 2);
    float v = bih[on] + bhh[on];
    if (badd) v += badd[on];
    bout[np] = v;
}

// W2p[n][k]: [0,512)=Wp_hi, [512,1024)=Wp_lo
__global__ __launch_bounds__(256) void prep_wp(const float* __restrict__ Wp,
                                               short* __restrict__ W2p) {
    int i = blockIdx.x * 256 + threadIdx.x;
    if (i >= 128 * 1024) return;
    int n = i >> 10, k = i & 1023;
    float w = Wp[(size_t)n * HID + (k & 511)];
    short hi = f2bf(w);
    W2p[i] = (k < 512) ? hi : f2bf(w - bf2f(hi));
}

// ---------------- device building blocks ----------------

// resident W load: 32 rows x K, k-major granules: lds[j*512 + r*16], j granule (8 bf16), r row
__device__ __forceinline__ void load_wres(char* lds, const short* Wg, int K) {
    const int tid = threadIdx.x;
    const int r = tid >> 4;                // 0..31
    const int cnt = K >> 7;                // (K/8)/16 granules per thread
    const int jb = (tid & 15) * cnt;
    for (int q = 0; q < cnt; ++q) {
        int j = jb + q;
        bf16x8 v = *(const bf16x8*)(Wg + (size_t)r * K + j * 8);
        *(bf16x8*)(lds + j * 512 + r * 16) = v;
    }
}

// 256(m) x 32(n') GEMM over K (hi|lo layout), resident W in LDS, A staged k-major dbuf
__device__ __forceinline__ void gemm_res256(
    const char* wres, char* abuf,
    const short* a0, int lda0, int len0,
    const short* a1, int lda1,
    int m0, int K, f32x4 acc[4])
{
    const int tid = threadIdx.x, w = tid >> 6, lane = tid & 63;
    const int wm = w >> 1, wn = w & 1;
    const int nkc = K >> 5;
    const int arow = lane & 15, akg = lane >> 4;

    auto stg = [&](int kc, char* d) {
        const int kb = kc << 5;
#pragma unroll
        for (int j = 0; j < 2; ++j) {
            int s = (w * 2 + j) * 64 + lane;
            int gg = s >> 8, r = s & 255;
            int col = kb + gg * 8;
            const short* src = (col < len0) ? a0 + (size_t)(m0 + r) * lda0 + col
                                            : a1 + (size_t)(m0 + r) * lda1 + (col - len0);
            async16(src, d + s * 16);
        }
    };

    stg(0, abuf);
    __syncthreads();
    for (int kc = 0; kc < nkc; ++kc) {
        char* cur = abuf + (kc & 1) * 16384;
        if (kc + 1 < nkc) stg(kc + 1, abuf + ((kc & 1) ^ 1) * 16384);
        bf16x8 fb = *(const bf16x8*)(wres + ((kc << 2) + akg) * 512 + (wn * 16 + arow) * 16);
        bf16x8 fa[4];
#pragma unroll
        for (int mi = 0; mi < 4; ++mi)
            fa[mi] = *(const bf16x8*)(cur + akg * 4096 + (wm * 64 + mi * 16 + arow) * 16);
#pragma unroll
        for (int mi = 0; mi < 4; ++mi)
            acc[mi] = __builtin_amdgcn_mfma_f32_16x16x32_bf16(fa[mi], fb, acc[mi], 0, 0, 0);
        __syncthreads();
    }
}

// LSTM pointwise epilogue for a 256x(8u x 4gate) block tile; gates staged in gl (32KB, swizzled)
__device__ __forceinline__ void cell_epi(
    char* gl, f32x4 acc[4], int m0, int np0, const float* bias_p,
    float* c, const float* mask_h, const float* mask_c,
    short* h2_out, short* h2_aux, const float* mask_aux)
{
    const int tid = threadIdx.x, w = tid >> 6, lane = tid & 63, wm = w >> 1, wn = w & 1;
    const int col = wn * 16 + (lane & 15);
#pragma unroll
    for (int mi = 0; mi < 4; ++mi) {
        int rowb = wm * 64 + mi * 16 + (lane >> 4) * 4;
#pragma unroll
        for (int r = 0; r < 4; ++r) {
            int m = rowb + r;
            *(float*)(gl + m * 128 + (((col >> 2) ^ (m & 7)) << 4) + ((col & 3) << 2)) = acc[mi][r];
        }
    }
    __syncthreads();
    const int ul = tid & 7, mq = tid >> 3;   // mq 0..63
    const int u = (np0 >> 2) + ul;
    const float4 bs = *(const float4*)(bias_p + np0 + ul * 4);
#pragma unroll
    for (int q = 0; q < 4; ++q) {
        int m = mq * 4 + q;
        int b = m0 + m;
        f32x4 gv = *(const f32x4*)(gl + m * 128 + ((ul ^ (m & 7)) << 4));
        float gi = gv[0] + bs.x, gf = gv[1] + bs.y, gg = gv[2] + bs.z, go = gv[3] + bs.w;
        size_t idx = (size_t)b * HID + u;
        float cv = c[idx];
        float cn = sigf(gf) * cv + sigf(gi) * tanhf(gg);
        float h  = sigf(go) * tanhf(cn);
        c[idx] = mask_c ? cn * mask_c[idx] : cn;
        float hm = mask_h ? h * mask_h[idx] : h;
        short hh = f2bf(hm);
        h2_out[(size_t)b * 1024 + u] = hh;
        h2_out[(size_t)b * 1024 + HID + u] = f2bf(hm - bf2f(hh));
        if (h2_aux) {
            float ha = h * mask_aux[idx];
            short ah = f2bf(ha);
            h2_aux[(size_t)b * 1024 + u] = ah;
            h2_aux[(size_t)b * 1024 + HID + u] = f2bf(ha - bf2f(ah));
        }
    }
    __syncthreads();
}

// 128(m) x 32(n) projection, streamed W, K=1024; writes dst[b][n] = gemm + bp[n]
__device__ void proj_phase(char* scr, const short* A, const short* Wp2,
                           int m0, int n0, float* dst, const float* bp)
{
    const int tid = threadIdx.x, w = tid >> 6, lane = tid & 63, wm = w >> 1, wn = w & 1;
    const int arow = lane & 15, akg = lane >> 4;
    auto stg = [&](int kc, char* d) {
        const int kb = kc << 5;
        { int s = w * 64 + lane; int gg = s >> 7, r = s & 127;
          async16(A + (size_t)(m0 + r) * 1024 + kb + gg * 8, d + s * 16); }
        if (w < 2) { int s = w * 64 + lane; int gg = s >> 5, r = s & 31;
          async16(Wp2 + (size_t)(n0 + r) * 1024 + kb + gg * 8, d + 8192 + s * 16); }
    };
    f32x4 acc[2]; acc[0] = (f32x4){0,0,0,0}; acc[1] = (f32x4){0,0,0,0};
    stg(0, scr);
    __syncthreads();
    for (int kc = 0; kc < 32; ++kc) {
        char* cur = scr + (kc & 1) * 10240;
        if (kc + 1 < 32) stg(kc + 1, scr + ((kc & 1) ^ 1) * 10240);
        bf16x8 fb = *(const bf16x8*)(cur + 8192 + akg * 512 + (wn * 16 + arow) * 16);
        bf16x8 fa[2];
#pragma unroll
        for (int mi = 0; mi < 2; ++mi)
            fa[mi] = *(const bf16x8*)(cur + akg * 2048 + (wm * 32 + mi * 16 + arow) * 16);
#pragma unroll
        for (int mi = 0; mi < 2; ++mi)
            acc[mi] = __builtin_amdgcn_mfma_f32_16x16x32_bf16(fa[mi], fb, acc[mi], 0, 0, 0);
        __syncthreads();
    }
    const int col = wn * 16 + (lane & 15);
#pragma unroll
    for (int mi = 0; mi < 2; ++mi) {
        int rowb = wm * 32 + mi * 16 + (lane >> 4) * 4;
#pragma unroll
        for (int r = 0; r < 4; ++r) {
            int m = rowb + r;
            *(float*)(scr + m * 128 + (((col >> 2) ^ (m & 7)) << 4) + ((col & 3) << 2)) = acc[mi][r];
        }
    }
    __syncthreads();
    const int nl = tid & 31, mb = (tid >> 5) * 8;
    const float bb = bp[n0 + nl];
#pragma unroll
    for (int q = 0; q < 8; ++q) {
        int m = mb + q;
        float v = *(float*)(scr + m * 128 + (((nl >> 2) ^ (m & 7)) << 4) + ((nl & 3) << 2));
        dst[(size_t)(m0 + m) * NIN + n0 + nl] = v + bb;
    }
    __syncthreads();
}

// ---------------- persistent kernels ----------------

__global__ void __launch_bounds__(512, 2) enc_kernel(
    const short* __restrict__ X2, const short* __restrict__ W0, const short* __restrict__ W1,
    short* hA0s, short* hA1s, short* hB0s, short* hB1s, short* hd0s, short* hd1s,
    float* cA, float* cB,
    const float* __restrict__ bias0, const float* __restrict__ bias1,
    const float* __restrict__ enc_mask, unsigned* cnt)
{
    extern __shared__ __align__(16) char lds[];
    const int bid = blockIdx.x;
    const int half = bid >> 7, hb = bid & 127;
    const int m0 = (hb & 1) * 256, np0 = (hb >> 1) * 32;
    const int K = half ? 2048 : 1280;
    const short* W = half ? W1 : W0;
    load_wres(lds, W + (size_t)np0 * K, K);
    char* scr = lds + (size_t)K * 64;     // 80KB (L0) / 128KB (L1)
    __syncthreads();
    unsigned ep = 0;
    for (int tt = 0; tt <= TST; ++tt) {
        const bool act = half ? (tt >= 1) : (tt < TST);
        if (act) {
            const int t = half ? tt - 1 : tt;
            f32x4 acc[4];
#pragma unroll
            for (int mi = 0; mi < 4; ++mi) acc[mi] = (f32x4){0, 0, 0, 0};
            const short* hAc = (t & 1) ? hA1s : hA0s;
            short*       hAn = (t & 1) ? hA0s : hA1s;
            const short* hBc = (t & 1) ? hB1s : hB0s;
            short*       hBn = (t & 1) ? hB0s : hB1s;
            short*       hdc = (t & 1) ? hd1s : hd0s;
            if (half) {
                gemm_res256(lds, scr, (t & 1) ? hd1s : hd0s, 1024, 1024, hBc, 1024, m0, 2048, acc);
                cell_epi(scr, acc, m0, np0, bias1, cB, nullptr, nullptr, hBn, nullptr, nullptr);
            } else {
                gemm_res256(lds, scr, X2 + (size_t)t * BAT * 256, 256, 256, hAc, 1024, m0, 1280, acc);
                cell_epi(scr, acc, m0, np0, bias0, cA, nullptr, nullptr, hAn,
                         hdc, enc_mask + (size_t)t * SBZ);
            }
        }
        gbar(cnt, 256u * (++ep));
    }
}

__global__ void __launch_bounds__(512, 2) dec_kernel(
    const short* __restrict__ Wd1, const short* __restrict__ Wd2, const short* __restrict__ W2p,
    short* hA0s, short* hA1s, short* hB0s, short* hB1s,
    float* cA, float* cB,
    const float* __restrict__ bias_d1, const float* __restrict__ bias_d2,
    const float* __restrict__ dec_h_mask, const float* __restrict__ dec_c_mask,
    const float* __restrict__ bp, float* pred_all, unsigned* cnt)
{
    extern __shared__ __align__(16) char lds[];
    const int bid = blockIdx.x, half = bid >> 7, hb = bid & 127;
    const int m0 = (hb & 1) * 256, np0 = (hb >> 1) * 32;
    const short* Wres = half ? Wd2 : Wd1;
    load_wres(lds, Wres + (size_t)np0 * 2048, 2048);
    char* scr = lds + 131072;
    const bool pj = (half == 1) && (hb < 16);
    const int m0p = (hb & 3) * 128, n0p = (hb >> 2) * 32;
    __syncthreads();
    unsigned ep = 0;
    for (int s = 0; s < HOR - 1; ++s) {
        const short* hAc = (s & 1) ? hA1s : hA0s;
        short*       hAn = (s & 1) ? hA0s : hA1s;
        const short* hBc = (s & 1) ? hB1s : hB0s;
        short*       hBn = (s & 1) ? hB0s : hB1s;
        if (half == 0) {
            f32x4 acc[4];
#pragma unroll
            for (int mi = 0; mi < 4; ++mi) acc[mi] = (f32x4){0, 0, 0, 0};
            gemm_res256(lds, scr, hBc, 1024, 1024, hAc, 1024, m0, 2048, acc);
            cell_epi(scr, acc, m0, np0, bias_d1, cA,
                     dec_h_mask + (size_t)s * SBZ, dec_c_mask + (size_t)s * SBZ,
                     hAn, nullptr, nullptr);
        } else if (pj) {
            proj_phase(scr, hBc, W2p, m0p, n0p, pred_all + (size_t)s * BAT * NIN, bp);
        }
        gbar(cnt, 256u * (++ep));
        if (half == 1) {
            f32x4 acc[4];
#pragma unroll
            for (int mi = 0; mi < 4; ++mi) acc[mi] = (f32x4){0, 0, 0, 0};
            gemm_res256(lds, scr, hAn, 1024, 1024, hBc, 1024, m0, 2048, acc);
            cell_epi(scr, acc, m0, np0, bias_d2, cB, nullptr, nullptr, hBn, nullptr, nullptr);
        }
        gbar(cnt, 256u * (++ep));
    }
    if (pj) proj_phase(scr, hB1s, W2p, m0p, n0p, pred_all + (size_t)(HOR - 1) * BAT * NIN, bp);
}

// out[(b*128+n)*32 + s] = pred_all[s][b*128+n]
__global__ __launch_bounds__(256) void transpose_out(const float* __restrict__ pred_all,
                                                     float* __restrict__ out) {
    __shared__ float tl[32][65];
    const int base = blockIdx.x * 64;
    const int tid = threadIdx.x;
    for (int i = tid; i < 32 * 64; i += 256) {
        int s = i >> 6, f = i & 63;
        tl[s][f] = pred_all[(size_t)s * (BAT * NIN) + base + f];
    }
    __syncthreads();
    for (int i = tid; i < 64 * 32; i += 256) {
        int f = i >> 5, s = i & 31;
        out[(size_t)(base + f) * HOR + s] = tl[s][f];
    }
}

// ---------------- host ----------------

extern "C" void kernel_launch(void* const* d_in, const int* in_sizes, int n_in,
                              void* d_out, int out_size, void* d_ws, size_t ws_size,
                              hipStream_t stream) {
    (void)in_sizes; (void)n_in; (void)out_size; (void)ws_size;
    const float* window = (const float*)d_in[0];
    const float* Wih0 = (const float*)d_in[1];
    const float* Whh0 = (const float*)d_in[2];
    const float* bih0 = (const float*)d_in[3];
    const float* bhh0 = (const float*)d_in[4];
    const float* Wih1 = (const float*)d_in[5];
    const float* Whh1 = (const float*)d_in[6];
    const float* bih1 = (const float*)d_in[7];
    const float* bhh1 = (const float*)d_in[8];
    const float* Wc1i = (const float*)d_in[9];
    const float* Wc1h = (const float*)d_in[10];
    const float* bc1i = (const float*)d_in[11];
    const float* bc1h = (const float*)d_in[12];
    const float* Wc2i = (const float*)d_in[13];
    const float* Wc2h = (const float*)d_in[14];
    const float* bc2i = (const float*)d_in[15];
    const float* bc2h = (const float*)d_in[16];
    const float* Wp   = (const float*)d_in[17];
    const float* bp   = (const float*)d_in[18];
    const float* enc_mask   = (const float*)d_in[19];
    const float* dec_h_mask = (const float*)d_in[20];
    const float* dec_c_mask = (const float*)d_in[21];
    float* out = (float*)d_out;

    char* base = (char*)d_ws;
    size_t off = 0;
    auto take = [&](size_t bytes) -> char* {
        off = (off + 255) & ~(size_t)255;
        char* r = base + off; off += bytes; return r;
    };
    short* W2e0 = (short*)take((size_t)2048 * 1280 * 2);
    short* W2e1 = (short*)take((size_t)2048 * 2048 * 2);
    short* W2d1 = (short*)take((size_t)2048 * 2048 * 2);   // fused [Wfuse|Wc1h] hi/lo
    short* W2d2 = (short*)take((size_t)2048 * 2048 * 2);
    short* W2p  = (short*)take((size_t)128 * 1024 * 2);
    float* Wfuse = (float*)take((size_t)2048 * 512 * 4);
    float* badd  = (float*)take((size_t)2048 * 4);
    float* bias0 = (float*)take((size_t)2048 * 4);
    float* bias1 = (float*)take((size_t)2048 * 4);
    float* biasd1 = (float*)take((size_t)2048 * 4);
    float* biasd2 = (float*)take((size_t)2048 * 4);
    short* hA2[2] = {(short*)take((size_t)BAT * 1024 * 2), (short*)take((size_t)BAT * 1024 * 2)};
    short* hB2[2] = {(short*)take((size_t)BAT * 1024 * 2), (short*)take((size_t)BAT * 1024 * 2)};
    short* hd2[2] = {(short*)take((size_t)BAT * 1024 * 2), (short*)take((size_t)BAT * 1024 * 2)};
    float* cA = (float*)take(SBZ * 4);
    float* cB = (float*)take(SBZ * 4);
    float* pred_all = (float*)take((size_t)HOR * BAT * NIN * 4);
    unsigned* cnts = (unsigned*)take(512);   // enc counter @ byte 0, dec counter @ byte 256 (IN range)
    short* X2 = (short*)take((size_t)TST * BAT * 256 * 2);

    // prep (re-done every call; deterministic)
    prep_fuse<<<(2048 * 512 + 255) / 256, 256, 0, stream>>>(Wc1i, Wp, Wfuse);
    prep_badd<<<8, 256, 0, stream>>>(Wc1i, bp, badd);
    prep_wp<<<(128 * 1024 + 255) / 256, 256, 0, stream>>>(Wp, W2p);
    prep_w<<<(2048 * 1280 + 255) / 256, 256, 0, stream>>>(Wih0, Whh0, W2e0, NIN, 1280);
    prep_w<<<(2048 * 2048 + 255) / 256, 256, 0, stream>>>(Wih1, Whh1, W2e1, HID, 2048);
    prep_w<<<(2048 * 2048 + 255) / 256, 256, 0, stream>>>(Wfuse, Wc1h, W2d1, HID, 2048);
    prep_w<<<(2048 * 2048 + 255) / 256, 256, 0, stream>>>(Wc2i, Wc2h, W2d2, HID, 2048);
    prep_bias<<<8, 256, 0, stream>>>(bih0, bhh0, nullptr, bias0);
    prep_bias<<<8, 256, 0, stream>>>(bih1, bhh1, nullptr, bias1);
    prep_bias<<<8, 256, 0, stream>>>(bc1i, bc1h, badd, biasd1);
    prep_bias<<<8, 256, 0, stream>>>(bc2i, bc2h, nullptr, biasd2);
    prep_x<<<(int)(((size_t)TST * BAT * NIN + 255) / 256), 256, 0, stream>>>(window, X2);
    hipMemsetAsync(hA2[0], 0, (size_t)BAT * 1024 * 2, stream);
    hipMemsetAsync(hB2[0], 0, (size_t)BAT * 1024 * 2, stream);
    hipMemsetAsync(cA, 0, SBZ * 4, stream);
    hipMemsetAsync(cB, 0, SBZ * 4, stream);
    hipMemsetAsync(cnts, 0, 512, stream);

    hipFuncSetAttribute((const void*)enc_kernel, hipFuncAttributeMaxDynamicSharedMemorySize, 163840);
    hipFuncSetAttribute((const void*)dec_kernel, hipFuncAttributeMaxDynamicSharedMemorySize, 163840);

    enc_kernel<<<256, 512, 163840, stream>>>(
        X2, W2e0, W2e1,
        hA2[0], hA2[1], hB2[0], hB2[1], hd2[0], hd2[1],
        cA, cB, bias0, bias1, enc_mask, cnts);

    dec_kernel<<<256, 512, 163840, stream>>>(
        W2d1, W2d2, W2p,
        hA2[0], hA2[1], hB2[0], hB2[1],
        cA, cB, biasd1, biasd2, dec_h_mask, dec_c_mask,
        bp, pred_all, cnts + 64);

    transpose_out<<<(BAT * NIN) / 64, 256, 0, stream>>>(pred_all, out);
}

// Round 6
// 12283.944 us; speedup vs baseline: 1.5592x; 1.5592x over previous
//
#include <hip/hip_runtime.h>
#include <math.h>

#define HID 512
#define BAT 512
#define NIN 128
#define TST 128
#define HOR 32
#define SBZ ((size_t)BAT * HID)

using bf16x8 = __attribute__((ext_vector_type(8))) __bf16;
using f32x4  = __attribute__((ext_vector_type(4))) float;

__device__ __forceinline__ float sigf(float x) { return 1.0f / (1.0f + expf(-x)); }

__device__ __forceinline__ short f2bf(float x) {
    union { float f; unsigned u; } v; v.f = x;
    unsigned r = (v.u + 0x7FFFu + ((v.u >> 16) & 1u)) >> 16;
    return (short)r;
}
__device__ __forceinline__ float bf2f(short s) {
    union { unsigned u; float f; } v; v.u = ((unsigned)(unsigned short)s) << 16;
    return v.f;
}
__device__ __forceinline__ void async16(const void* g, void* l) {
    __builtin_amdgcn_global_load_lds(
        (const __attribute__((address_space(1))) void*)g,
        (__attribute__((address_space(3))) void*)l, 16, 0, 0);
}

// device-scope grid barrier: monotone counter.
// Arrive: release add (one wbl2 per block). Poll: RELAXED agent loads (sc1-routed,
// coherent, NO buffer_inv per poll — the acquire-inv-per-poll was round 5's 91us/epoch).
// Exit: single acquire fence.
__device__ __forceinline__ void gbar(unsigned* cnt, unsigned target) {
    __syncthreads();
    if (threadIdx.x == 0) {
        __hip_atomic_fetch_add(cnt, 1u, __ATOMIC_RELEASE, __HIP_MEMORY_SCOPE_AGENT);
        int spin = 0;
        while (__hip_atomic_load(cnt, __ATOMIC_RELAXED, __HIP_MEMORY_SCOPE_AGENT) < target) {
            __builtin_amdgcn_s_sleep(8);
            if (((++spin) & 255) == 0)   // progress insurance; never hit in steady state
                __hip_atomic_fetch_add(cnt, 0u, __ATOMIC_RELAXED, __HIP_MEMORY_SCOPE_AGENT);
        }
        __builtin_amdgcn_fence(__ATOMIC_ACQUIRE, "agent");
    }
    __syncthreads();
}

// ---------------- prep kernels ----------------

// permuted weight rows: n' = u*4 + gate  <->  orig row gate*512 + u
// cols: [0,Kx)=Wih_hi [Kx,2Kx)=Wih_lo [2Kx,2Kx+512)=Whh_hi [2Kx+512,Kp)=Whh_lo
__global__ __launch_bounds__(256) void prep_w(const float* __restrict__ Wih,
                                              const float* __restrict__ Whh,
                                              short* __restrict__ W2, int Kx, int Kp) {
    size_t i = (size_t)blockIdx.x * 256 + threadIdx.x;
    if (i >= (size_t)2048 * Kp) return;
    int np = (int)(i / Kp), kp = (int)(i % Kp);
    int u = np >> 2, gate = np & 3;
    int on = gate * HID + u;
    float w; bool islo = false;
    if (kp < Kx)                { w = Wih[(size_t)on * Kx + kp]; }
    else if (kp < 2 * Kx)       { w = Wih[(size_t)on * Kx + (kp - Kx)]; islo = true; }
    else if (kp < 2 * Kx + HID) { w = Whh[(size_t)on * HID + (kp - 2 * Kx)]; }
    else                        { w = Whh[(size_t)on * HID + (kp - 2 * Kx - HID)]; islo = true; }
    short hi = f2bf(w);
    W2[i] = islo ? f2bf(w - bf2f(hi)) : hi;
}

__global__ __launch_bounds__(256) void prep_x(const float* __restrict__ window,
                                              short* __restrict__ x2) {
    size_t i = (size_t)blockIdx.x * 256 + threadIdx.x;
    if (i >= (size_t)TST * BAT * NIN) return;
    int n = (int)(i & 127);
    int b = (int)((i >> 7) & 511);
    int t = (int)(i >> 16);
    float x = window[(size_t)b * (TST * NIN) + (size_t)t * NIN + n];
    short hi = f2bf(x);
    short* dst = x2 + (size_t)t * (BAT * 256) + (size_t)b * 256;
    dst[n] = hi;
    dst[128 + n] = f2bf(x - bf2f(hi));
}

__global__ __launch_bounds__(256) void prep_fuse(const float* __restrict__ Wc1i,
                                                 const float* __restrict__ Wp,
                                                 float* __restrict__ Wfuse) {
    size_t i = (size_t)blockIdx.x * 256 + threadIdx.x;
    if (i >= (size_t)2048 * 512) return;
    int on = (int)(i >> 9), k = (int)(i & 511);
    float s = 0.f;
    for (int n = 0; n < NIN; ++n) s += Wc1i[(size_t)on * NIN + n] * Wp[(size_t)n * HID + k];
    Wfuse[i] = s;
}

__global__ __launch_bounds__(256) void prep_badd(const float* __restrict__ Wc1i,
                                                 const float* __restrict__ bp,
                                                 float* __restrict__ badd) {
    int on = blockIdx.x * 256 + threadIdx.x;
    if (on >= 2048) return;
    float s = 0.f;
    for (int n = 0; n < NIN; ++n) s += Wc1i[(size_t)on * NIN + n] * bp[n];
    badd[on] = s;
}

// bias_p[n'] = bih[on]+bhh[on](+badd[on]), n' = u*4+gate
__global__ __launch_bounds__(256) void prep_bias(const float* __restrict__ bih,
                                                 const float* __restrict__ bhh,
                                                 const float* __restrict__ badd,
                                                 float* __restrict__ bout) {
    int np = blockIdx.x * 256 + threadIdx.x;
    if (np >= 2048) return;
    int on = (np & 3) * HID + (np >> 2);
    float v = bih[on] + bhh[on];
    if (badd) v += badd[on];
    bout[np] = v;
}

// W2p[n][k]: [0,512)=Wp_hi, [512,1024)=Wp_lo
__global__ __launch_bounds__(256) void prep_wp(const float* __restrict__ Wp,
                                               short* __restrict__ W2p) {
    int i = blockIdx.x * 256 + threadIdx.x;
    if (i >= 128 * 1024) return;
    int n = i >> 10, k = i & 1023;
    float w = Wp[(size_t)n * HID + (k & 511)];
    short hi = f2bf(w);
    W2p[i] = (k < 512) ? hi : f2bf(w - bf2f(hi));
}

// ---------------- device building blocks ----------------

// resident W load: 32 rows x K, k-major granules: lds[j*512 + r*16], j granule (8 bf16), r row
__device__ __forceinline__ void load_wres(char* lds, const short* Wg, int K) {
    const int tid = threadIdx.x;
    const int r = tid >> 4;                // 0..31
    const int cnt = K >> 7;                // (K/8)/16 granules per thread
    const int jb = (tid & 15) * cnt;
    for (int q = 0; q < cnt; ++q) {
        int j = jb + q;
        bf16x8 v = *(const bf16x8*)(Wg + (size_t)r * K + j * 8);
        *(bf16x8*)(lds + j * 512 + r * 16) = v;
    }
}

// 256(m) x 32(n') GEMM over K (hi|lo layout), resident W in LDS, A staged k-major dbuf
__device__ __forceinline__ void gemm_res256(
    const char* wres, char* abuf,
    const short* a0, int lda0, int len0,
    const short* a1, int lda1,
    int m0, int K, f32x4 acc[4])
{
    const int tid = threadIdx.x, w = tid >> 6, lane = tid & 63;
    const int wm = w >> 1, wn = w & 1;
    const int nkc = K >> 5;
    const int arow = lane & 15, akg = lane >> 4;

    auto stg = [&](int kc, char* d) {
        const int kb = kc << 5;
#pragma unroll
        for (int j = 0; j < 2; ++j) {
            int s = (w * 2 + j) * 64 + lane;
            int gg = s >> 8, r = s & 255;
            int col = kb + gg * 8;
            const short* src = (col < len0) ? a0 + (size_t)(m0 + r) * lda0 + col
                                            : a1 + (size_t)(m0 + r) * lda1 + (col - len0);
            async16(src, d + s * 16);
        }
    };

    stg(0, abuf);
    __syncthreads();
    for (int kc = 0; kc < nkc; ++kc) {
        char* cur = abuf + (kc & 1) * 16384;
        if (kc + 1 < nkc) stg(kc + 1, abuf + ((kc & 1) ^ 1) * 16384);
        bf16x8 fb = *(const bf16x8*)(wres + ((kc << 2) + akg) * 512 + (wn * 16 + arow) * 16);
        bf16x8 fa[4];
#pragma unroll
        for (int mi = 0; mi < 4; ++mi)
            fa[mi] = *(const bf16x8*)(cur + akg * 4096 + (wm * 64 + mi * 16 + arow) * 16);
#pragma unroll
        for (int mi = 0; mi < 4; ++mi)
            acc[mi] = __builtin_amdgcn_mfma_f32_16x16x32_bf16(fa[mi], fb, acc[mi], 0, 0, 0);
        __syncthreads();
    }
}

// LSTM pointwise epilogue for a 256x(8u x 4gate) block tile; gates staged in gl (32KB, swizzled)
__device__ __forceinline__ void cell_epi(
    char* gl, f32x4 acc[4], int m0, int np0, const float* bias_p,
    float* c, const float* mask_h, const float* mask_c,
    short* h2_out, short* h2_aux, const float* mask_aux)
{
    const int tid = threadIdx.x, w = tid >> 6, lane = tid & 63, wm = w >> 1, wn = w & 1;
    const int col = wn * 16 + (lane & 15);
#pragma unroll
    for (int mi = 0; mi < 4; ++mi) {
        int rowb = wm * 64 + mi * 16 + (lane >> 4) * 4;
#pragma unroll
        for (int r = 0; r < 4; ++r) {
            int m = rowb + r;
            *(float*)(gl + m * 128 + (((col >> 2) ^ (m & 7)) << 4) + ((col & 3) << 2)) = acc[mi][r];
        }
    }
    __syncthreads();
    const int ul = tid & 7, mq = tid >> 3;   // mq 0..63
    const int u = (np0 >> 2) + ul;
    const float4 bs = *(const float4*)(bias_p + np0 + ul * 4);
#pragma unroll
    for (int q = 0; q < 4; ++q) {
        int m = mq * 4 + q;
        int b = m0 + m;
        f32x4 gv = *(const f32x4*)(gl + m * 128 + ((ul ^ (m & 7)) << 4));
        float gi = gv[0] + bs.x, gf = gv[1] + bs.y, gg = gv[2] + bs.z, go = gv[3] + bs.w;
        size_t idx = (size_t)b * HID + u;
        float cv = c[idx];
        float cn = sigf(gf) * cv + sigf(gi) * tanhf(gg);
        float h  = sigf(go) * tanhf(cn);
        c[idx] = mask_c ? cn * mask_c[idx] : cn;
        float hm = mask_h ? h * mask_h[idx] : h;
        short hh = f2bf(hm);
        h2_out[(size_t)b * 1024 + u] = hh;
        h2_out[(size_t)b * 1024 + HID + u] = f2bf(hm - bf2f(hh));
        if (h2_aux) {
            float ha = h * mask_aux[idx];
            short ah = f2bf(ha);
            h2_aux[(size_t)b * 1024 + u] = ah;
            h2_aux[(size_t)b * 1024 + HID + u] = f2bf(ha - bf2f(ah));
        }
    }
    __syncthreads();
}

// 128(m) x 32(n) projection, streamed W, K=1024; writes dst[b][n] = gemm + bp[n]
__device__ void proj_phase(char* scr, const short* A, const short* Wp2,
                           int m0, int n0, float* dst, const float* bp)
{
    const int tid = threadIdx.x, w = tid >> 6, lane = tid & 63, wm = w >> 1, wn = w & 1;
    const int arow = lane & 15, akg = lane >> 4;
    auto stg = [&](int kc, char* d) {
        const int kb = kc << 5;
        { int s = w * 64 + lane; int gg = s >> 7, r = s & 127;
          async16(A + (size_t)(m0 + r) * 1024 + kb + gg * 8, d + s * 16); }
        if (w < 2) { int s = w * 64 + lane; int gg = s >> 5, r = s & 31;
          async16(Wp2 + (size_t)(n0 + r) * 1024 + kb + gg * 8, d + 8192 + s * 16); }
    };
    f32x4 acc[2]; acc[0] = (f32x4){0,0,0,0}; acc[1] = (f32x4){0,0,0,0};
    stg(0, scr);
    __syncthreads();
    for (int kc = 0; kc < 32; ++kc) {
        char* cur = scr + (kc & 1) * 10240;
        if (kc + 1 < 32) stg(kc + 1, scr + ((kc & 1) ^ 1) * 10240);
        bf16x8 fb = *(const bf16x8*)(cur + 8192 + akg * 512 + (wn * 16 + arow) * 16);
        bf16x8 fa[2];
#pragma unroll
        for (int mi = 0; mi < 2; ++mi)
            fa[mi] = *(const bf16x8*)(cur + akg * 2048 + (wm * 32 + mi * 16 + arow) * 16);
#pragma unroll
        for (int mi = 0; mi < 2; ++mi)
            acc[mi] = __builtin_amdgcn_mfma_f32_16x16x32_bf16(fa[mi], fb, acc[mi], 0, 0, 0);
        __syncthreads();
    }
    const int col = wn * 16 + (lane & 15);
#pragma unroll
    for (int mi = 0; mi < 2; ++mi) {
        int rowb = wm * 32 + mi * 16 + (lane >> 4) * 4;
#pragma unroll
        for (int r = 0; r < 4; ++r) {
            int m = rowb + r;
            *(float*)(scr + m * 128 + (((col >> 2) ^ (m & 7)) << 4) + ((col & 3) << 2)) = acc[mi][r];
        }
    }
    __syncthreads();
    const int nl = tid & 31, mb = (tid >> 5) * 8;
    const float bb = bp[n0 + nl];
#pragma unroll
    for (int q = 0; q < 8; ++q) {
        int m = mb + q;
        float v = *(float*)(scr + m * 128 + (((nl >> 2) ^ (m & 7)) << 4) + ((nl & 3) << 2));
        dst[(size_t)(m0 + m) * NIN + n0 + nl] = v + bb;
    }
    __syncthreads();
}

// ---------------- persistent kernels ----------------

__global__ void __launch_bounds__(512, 2) enc_kernel(
    const short* __restrict__ X2, const short* __restrict__ W0, const short* __restrict__ W1,
    short* hA0s, short* hA1s, short* hB0s, short* hB1s, short* hd0s, short* hd1s,
    float* cA, float* cB,
    const float* __restrict__ bias0, const float* __restrict__ bias1,
    const float* __restrict__ enc_mask, unsigned* cnt)
{
    extern __shared__ __align__(16) char lds[];
    const int bid = blockIdx.x;
    const int half = bid >> 7, hb = bid & 127;
    const int m0 = (hb & 1) * 256, np0 = (hb >> 1) * 32;
    const int K = half ? 2048 : 1280;
    const short* W = half ? W1 : W0;
    load_wres(lds, W + (size_t)np0 * K, K);
    char* scr = lds + (size_t)K * 64;     // 80KB (L0) / 128KB (L1)
    __syncthreads();
    unsigned ep = 0;
    for (int tt = 0; tt <= TST; ++tt) {
        const bool act = half ? (tt >= 1) : (tt < TST);
        if (act) {
            const int t = half ? tt - 1 : tt;
            f32x4 acc[4];
#pragma unroll
            for (int mi = 0; mi < 4; ++mi) acc[mi] = (f32x4){0, 0, 0, 0};
            const short* hAc = (t & 1) ? hA1s : hA0s;
            short*       hAn = (t & 1) ? hA0s : hA1s;
            const short* hBc = (t & 1) ? hB1s : hB0s;
            short*       hBn = (t & 1) ? hB0s : hB1s;
            short*       hdc = (t & 1) ? hd1s : hd0s;
            if (half) {
                gemm_res256(lds, scr, (t & 1) ? hd1s : hd0s, 1024, 1024, hBc, 1024, m0, 2048, acc);
                cell_epi(scr, acc, m0, np0, bias1, cB, nullptr, nullptr, hBn, nullptr, nullptr);
            } else {
                gemm_res256(lds, scr, X2 + (size_t)t * BAT * 256, 256, 256, hAc, 1024, m0, 1280, acc);
                cell_epi(scr, acc, m0, np0, bias0, cA, nullptr, nullptr, hAn,
                         hdc, enc_mask + (size_t)t * SBZ);
            }
        }
        gbar(cnt, 256u * (++ep));
    }
}

__global__ void __launch_bounds__(512, 2) dec_kernel(
    const short* __restrict__ Wd1, const short* __restrict__ Wd2, const short* __restrict__ W2p,
    short* hA0s, short* hA1s, short* hB0s, short* hB1s,
    float* cA, float* cB,
    const float* __restrict__ bias_d1, const float* __restrict__ bias_d2,
    const float* __restrict__ dec_h_mask, const float* __restrict__ dec_c_mask,
    const float* __restrict__ bp, float* pred_all, unsigned* cnt)
{
    extern __shared__ __align__(16) char lds[];
    const int bid = blockIdx.x, half = bid >> 7, hb = bid & 127;
    const int m0 = (hb & 1) * 256, np0 = (hb >> 1) * 32;
    const short* Wres = half ? Wd2 : Wd1;
    load_wres(lds, Wres + (size_t)np0 * 2048, 2048);
    char* scr = lds + 131072;
    const bool pj = (half == 1) && (hb < 16);
    const int m0p = (hb & 3) * 128, n0p = (hb >> 2) * 32;
    __syncthreads();
    unsigned ep = 0;
    for (int s = 0; s < HOR - 1; ++s) {
        const short* hAc = (s & 1) ? hA1s : hA0s;
        short*       hAn = (s & 1) ? hA0s : hA1s;
        const short* hBc = (s & 1) ? hB1s : hB0s;
        short*       hBn = (s & 1) ? hB0s : hB1s;
        if (half == 0) {
            f32x4 acc[4];
#pragma unroll
            for (int mi = 0; mi < 4; ++mi) acc[mi] = (f32x4){0, 0, 0, 0};
            gemm_res256(lds, scr, hBc, 1024, 1024, hAc, 1024, m0, 2048, acc);
            cell_epi(scr, acc, m0, np0, bias_d1, cA,
                     dec_h_mask + (size_t)s * SBZ, dec_c_mask + (size_t)s * SBZ,
                     hAn, nullptr, nullptr);
        } else if (pj) {
            proj_phase(scr, hBc, W2p, m0p, n0p, pred_all + (size_t)s * BAT * NIN, bp);
        }
        gbar(cnt, 256u * (++ep));
        if (half == 1) {
            f32x4 acc[4];
#pragma unroll
            for (int mi = 0; mi < 4; ++mi) acc[mi] = (f32x4){0, 0, 0, 0};
            gemm_res256(lds, scr, hAn, 1024, 1024, hBc, 1024, m0, 2048, acc);
            cell_epi(scr, acc, m0, np0, bias_d2, cB, nullptr, nullptr, hBn, nullptr, nullptr);
        }
        gbar(cnt, 256u * (++ep));
    }
    if (pj) proj_phase(scr, hB1s, W2p, m0p, n0p, pred_all + (size_t)(HOR - 1) * BAT * NIN, bp);
}

// out[(b*128+n)*32 + s] = pred_all[s][b*128+n]
__global__ __launch_bounds__(256) void transpose_out(const float* __restrict__ pred_all,
                                                     float* __restrict__ out) {
    __shared__ float tl[32][65];
    const int base = blockIdx.x * 64;
    const int tid = threadIdx.x;
    for (int i = tid; i < 32 * 64; i += 256) {
        int s = i >> 6, f = i & 63;
        tl[s][f] = pred_all[(size_t)s * (BAT * NIN) + base + f];
    }
    __syncthreads();
    for (int i = tid; i < 64 * 32; i += 256) {
        int f = i >> 5, s = i & 31;
        out[(size_t)(base + f) * HOR + s] = tl[s][f];
    }
}

// ---------------- host ----------------

extern "C" void kernel_launch(void* const* d_in, const int* in_sizes, int n_in,
                              void* d_out, int out_size, void* d_ws, size_t ws_size,
                              hipStream_t stream) {
    (void)in_sizes; (void)n_in; (void)out_size; (void)ws_size;
    const float* window = (const float*)d_in[0];
    const float* Wih0 = (const float*)d_in[1];
    const float* Whh0 = (const float*)d_in[2];
    const float* bih0 = (const float*)d_in[3];
    const float* bhh0 = (const float*)d_in[4];
    const float* Wih1 = (const float*)d_in[5];
    const float* Whh1 = (const float*)d_in[6];
    const float* bih1 = (const float*)d_in[7];
    const float* bhh1 = (const float*)d_in[8];
    const float* Wc1i = (const float*)d_in[9];
    const float* Wc1h = (const float*)d_in[10];
    const float* bc1i = (const float*)d_in[11];
    const float* bc1h = (const float*)d_in[12];
    const float* Wc2i = (const float*)d_in[13];
    const float* Wc2h = (const float*)d_in[14];
    const float* bc2i = (const float*)d_in[15];
    const float* bc2h = (const float*)d_in[16];
    const float* Wp   = (const float*)d_in[17];
    const float* bp   = (const float*)d_in[18];
    const float* enc_mask   = (const float*)d_in[19];
    const float* dec_h_mask = (const float*)d_in[20];
    const float* dec_c_mask = (const float*)d_in[21];
    float* out = (float*)d_out;

    char* base = (char*)d_ws;
    size_t off = 0;
    auto take = [&](size_t bytes) -> char* {
        off = (off + 255) & ~(size_t)255;
        char* r = base + off; off += bytes; return r;
    };
    short* W2e0 = (short*)take((size_t)2048 * 1280 * 2);
    short* W2e1 = (short*)take((size_t)2048 * 2048 * 2);
    short* W2d1 = (short*)take((size_t)2048 * 2048 * 2);   // fused [Wfuse|Wc1h] hi/lo
    short* W2d2 = (short*)take((size_t)2048 * 2048 * 2);
    short* W2p  = (short*)take((size_t)128 * 1024 * 2);
    float* Wfuse = (float*)take((size_t)2048 * 512 * 4);
    float* badd  = (float*)take((size_t)2048 * 4);
    float* bias0 = (float*)take((size_t)2048 * 4);
    float* bias1 = (float*)take((size_t)2048 * 4);
    float* biasd1 = (float*)take((size_t)2048 * 4);
    float* biasd2 = (float*)take((size_t)2048 * 4);
    short* hA2[2] = {(short*)take((size_t)BAT * 1024 * 2), (short*)take((size_t)BAT * 1024 * 2)};
    short* hB2[2] = {(short*)take((size_t)BAT * 1024 * 2), (short*)take((size_t)BAT * 1024 * 2)};
    short* hd2[2] = {(short*)take((size_t)BAT * 1024 * 2), (short*)take((size_t)BAT * 1024 * 2)};
    float* cA = (float*)take(SBZ * 4);
    float* cB = (float*)take(SBZ * 4);
    float* pred_all = (float*)take((size_t)HOR * BAT * NIN * 4);
    unsigned* cnts = (unsigned*)take(512);   // enc counter @ byte 0, dec counter @ byte 256
    short* X2 = (short*)take((size_t)TST * BAT * 256 * 2);

    // prep (re-done every call; deterministic)
    prep_fuse<<<(2048 * 512 + 255) / 256, 256, 0, stream>>>(Wc1i, Wp, Wfuse);
    prep_badd<<<8, 256, 0, stream>>>(Wc1i, bp, badd);
    prep_wp<<<(128 * 1024 + 255) / 256, 256, 0, stream>>>(Wp, W2p);
    prep_w<<<(2048 * 1280 + 255) / 256, 256, 0, stream>>>(Wih0, Whh0, W2e0, NIN, 1280);
    prep_w<<<(2048 * 2048 + 255) / 256, 256, 0, stream>>>(Wih1, Whh1, W2e1, HID, 2048);
    prep_w<<<(2048 * 2048 + 255) / 256, 256, 0, stream>>>(Wfuse, Wc1h, W2d1, HID, 2048);
    prep_w<<<(2048 * 2048 + 255) / 256, 256, 0, stream>>>(Wc2i, Wc2h, W2d2, HID, 2048);
    prep_bias<<<8, 256, 0, stream>>>(bih0, bhh0, nullptr, bias0);
    prep_bias<<<8, 256, 0, stream>>>(bih1, bhh1, nullptr, bias1);
    prep_bias<<<8, 256, 0, stream>>>(bc1i, bc1h, badd, biasd1);
    prep_bias<<<8, 256, 0, stream>>>(bc2i, bc2h, nullptr, biasd2);
    prep_x<<<(int)(((size_t)TST * BAT * NIN + 255) / 256), 256, 0, stream>>>(window, X2);
    hipMemsetAsync(hA2[0], 0, (size_t)BAT * 1024 * 2, stream);
    hipMemsetAsync(hB2[0], 0, (size_t)BAT * 1024 * 2, stream);
    hipMemsetAsync(cA, 0, SBZ * 4, stream);
    hipMemsetAsync(cB, 0, SBZ * 4, stream);
    hipMemsetAsync(cnts, 0, 512, stream);

    hipFuncSetAttribute((const void*)enc_kernel, hipFuncAttributeMaxDynamicSharedMemorySize, 163840);
    hipFuncSetAttribute((const void*)dec_kernel, hipFuncAttributeMaxDynamicSharedMemorySize, 163840);

    enc_kernel<<<256, 512, 163840, stream>>>(
        X2, W2e0, W2e1,
        hA2[0], hA2[1], hB2[0], hB2[1], hd2[0], hd2[1],
        cA, cB, bias0, bias1, enc_mask, cnts);

    dec_kernel<<<256, 512, 163840, stream>>>(
        W2d1, W2d2, W2p,
        hA2[0], hA2[1], hB2[0], hB2[1],
        cA, cB, biasd1, biasd2, dec_h_mask, dec_c_mask,
        bp, pred_all, cnts + 64);

    transpose_out<<<(BAT * NIN) / 64, 256, 0, stream>>>(pred_all, out);
}

// Round 7
// 9047.733 us; speedup vs baseline: 2.1169x; 1.3577x over previous
//
#include <hip/hip_runtime.h>
#include <math.h>

#define HID 512
#define BAT 512
#define NIN 128
#define TST 128
#define HOR 32
#define SBZ ((size_t)BAT * HID)

using bf16x8 = __attribute__((ext_vector_type(8))) __bf16;
using f32x4  = __attribute__((ext_vector_type(4))) float;

__device__ __forceinline__ float sigf(float x) { return 1.0f / (1.0f + expf(-x)); }

__device__ __forceinline__ short f2bf(float x) {
    union { float f; unsigned u; } v; v.f = x;
    unsigned r = (v.u + 0x7FFFu + ((v.u >> 16) & 1u)) >> 16;
    return (short)r;
}
__device__ __forceinline__ float bf2f(short s) {
    union { unsigned u; float f; } v; v.u = ((unsigned)(unsigned short)s) << 16;
    return v.f;
}
__device__ __forceinline__ void async16(const void* g, void* l) {
    __builtin_amdgcn_global_load_lds(
        (const __attribute__((address_space(1))) void*)g,
        (__attribute__((address_space(3))) void*)l, 16, 0, 0);
}

// ---- hierarchical grid barrier ----
// bar layout (u32 idx): leaf[g] at g*32 (g=0..31, 8 blocks each), root at 1024, flag at 1056.
// Arrive: release-add to leaf (parallel across 32 lines); leaf-last release-adds root;
// root-last release-stores flag. Everyone polls flag with RELAXED loads (read-only line,
// no RMW ping-pong), then one acquire fence.
__device__ __forceinline__ void gbar2(unsigned* bar, int bid, unsigned ep) {
    __syncthreads();
    if (threadIdx.x == 0) {
        unsigned* leaf = bar + ((unsigned)bid >> 3) * 32;
        unsigned* root = bar + 1024;
        unsigned* flag = bar + 1056;
        unsigned old = __hip_atomic_fetch_add(leaf, 1u, __ATOMIC_RELEASE, __HIP_MEMORY_SCOPE_AGENT);
        if (old == 8u * ep - 1u) {
            unsigned ro = __hip_atomic_fetch_add(root, 1u, __ATOMIC_RELEASE, __HIP_MEMORY_SCOPE_AGENT);
            if (ro == 32u * ep - 1u)
                __hip_atomic_store(flag, ep, __ATOMIC_RELEASE, __HIP_MEMORY_SCOPE_AGENT);
        }
        while (__hip_atomic_load(flag, __ATOMIC_RELAXED, __HIP_MEMORY_SCOPE_AGENT) < ep)
            __builtin_amdgcn_s_sleep(2);
        __builtin_amdgcn_fence(__ATOMIC_ACQUIRE, "agent");
    }
    __syncthreads();
}

// ---------------- prep kernels ----------------

// permuted weight rows: n' = u*4 + gate  <->  orig row gate*512 + u
// cols: [0,Kx)=Wih_hi [Kx,2Kx)=Wih_lo [2Kx,2Kx+512)=Whh_hi [2Kx+512,Kp)=Whh_lo
__global__ __launch_bounds__(256) void prep_w(const float* __restrict__ Wih,
                                              const float* __restrict__ Whh,
                                              short* __restrict__ W2, int Kx, int Kp) {
    size_t i = (size_t)blockIdx.x * 256 + threadIdx.x;
    if (i >= (size_t)2048 * Kp) return;
    int np = (int)(i / Kp), kp = (int)(i % Kp);
    int u = np >> 2, gate = np & 3;
    int on = gate * HID + u;
    float w; bool islo = false;
    if (kp < Kx)                { w = Wih[(size_t)on * Kx + kp]; }
    else if (kp < 2 * Kx)       { w = Wih[(size_t)on * Kx + (kp - Kx)]; islo = true; }
    else if (kp < 2 * Kx + HID) { w = Whh[(size_t)on * HID + (kp - 2 * Kx)]; }
    else                        { w = Whh[(size_t)on * HID + (kp - 2 * Kx - HID)]; islo = true; }
    short hi = f2bf(w);
    W2[i] = islo ? f2bf(w - bf2f(hi)) : hi;
}

__global__ __launch_bounds__(256) void prep_x(const float* __restrict__ window,
                                              short* __restrict__ x2) {
    size_t i = (size_t)blockIdx.x * 256 + threadIdx.x;
    if (i >= (size_t)TST * BAT * NIN) return;
    int n = (int)(i & 127);
    int b = (int)((i >> 7) & 511);
    int t = (int)(i >> 16);
    float x = window[(size_t)b * (TST * NIN) + (size_t)t * NIN + n];
    short hi = f2bf(x);
    short* dst = x2 + (size_t)t * (BAT * 256) + (size_t)b * 256;
    dst[n] = hi;
    dst[128 + n] = f2bf(x - bf2f(hi));
}

__global__ __launch_bounds__(256) void prep_fuse(const float* __restrict__ Wc1i,
                                                 const float* __restrict__ Wp,
                                                 float* __restrict__ Wfuse) {
    size_t i = (size_t)blockIdx.x * 256 + threadIdx.x;
    if (i >= (size_t)2048 * 512) return;
    int on = (int)(i >> 9), k = (int)(i & 511);
    float s = 0.f;
    for (int n = 0; n < NIN; ++n) s += Wc1i[(size_t)on * NIN + n] * Wp[(size_t)n * HID + k];
    Wfuse[i] = s;
}

__global__ __launch_bounds__(256) void prep_badd(const float* __restrict__ Wc1i,
                                                 const float* __restrict__ bp,
                                                 float* __restrict__ badd) {
    int on = blockIdx.x * 256 + threadIdx.x;
    if (on >= 2048) return;
    float s = 0.f;
    for (int n = 0; n < NIN; ++n) s += Wc1i[(size_t)on * NIN + n] * bp[n];
    badd[on] = s;
}

__global__ __launch_bounds__(256) void prep_bias(const float* __restrict__ bih,
                                                 const float* __restrict__ bhh,
                                                 const float* __restrict__ badd,
                                                 float* __restrict__ bout) {
    int np = blockIdx.x * 256 + threadIdx.x;
    if (np >= 2048) return;
    int on = (np & 3) * HID + (np >> 2);
    float v = bih[on] + bhh[on];
    if (badd) v += badd[on];
    bout[np] = v;
}

__global__ __launch_bounds__(256) void prep_wp(const float* __restrict__ Wp,
                                               short* __restrict__ W2p) {
    int i = blockIdx.x * 256 + threadIdx.x;
    if (i >= 128 * 1024) return;
    int n = i >> 10, k = i & 1023;
    float w = Wp[(size_t)n * HID + (k & 511)];
    short hi = f2bf(w);
    W2p[i] = (k < 512) ? hi : f2bf(w - bf2f(hi));
}

// ---------------- device building blocks ----------------

// resident W: 32 rows x K, k-major granules: lds[j*512 + r*16], j = k-granule, r = n'-row
__device__ __forceinline__ void load_wres(char* lds, const short* Wg, int K) {
    const int tid = threadIdx.x;
    const int r = tid >> 4;
    const int cnt = K >> 7;
    const int jb = (tid & 15) * cnt;
    for (int q = 0; q < cnt; ++q) {
        int j = jb + q;
        bf16x8 v = *(const bf16x8*)(Wg + (size_t)r * K + j * 8);
        *(bf16x8*)(lds + j * 512 + r * 16) = v;
    }
}

// Wave-private GEMM: 32(m) x 32(n') over K, A loaded global->VGPR with depth-8
// pipeline (fully unrolled => static slot indices), W read from resident LDS.
// NO block barriers inside.
template<int NKC>
__device__ __forceinline__ void gemm_regA(
    const char* wres,
    const short* __restrict__ a0, int lda0, int len0,
    const short* __restrict__ a1, int lda1,
    int mrow, f32x4 acc[2][2])
{
    const int lane = threadIdx.x & 63;
    const int arow = lane & 15;
    const int akg  = lane >> 4;
    const int ko   = akg << 3;
    const short* b00 = a0 + (size_t)(mrow + arow) * lda0;
    const short* b01 = a0 + (size_t)(mrow + 16 + arow) * lda0;
    const short* b10 = a1 + (size_t)(mrow + arow) * lda1;
    const short* b11 = a1 + (size_t)(mrow + 16 + arow) * lda1;

    bf16x8 p0[8], p1[8];
#pragma unroll
    for (int i = 0; i < 8; ++i) {
        const int col = (i << 5) + ko;
        p0[i] = *(const bf16x8*)((col < len0) ? (b00 + col) : (b10 + (col - len0)));
        p1[i] = *(const bf16x8*)((col < len0) ? (b01 + col) : (b11 + (col - len0)));
    }
#pragma unroll
    for (int kc = 0; kc < NKC; ++kc) {
        const int sl = kc & 7;
        const bf16x8 fa0 = p0[sl];
        const bf16x8 fa1 = p1[sl];
        const bf16x8 fb0 = *(const bf16x8*)(wres + (size_t)(((kc << 2) + akg) << 9) + (arow << 4));
        const bf16x8 fb1 = *(const bf16x8*)(wres + (size_t)(((kc << 2) + akg) << 9) + ((16 + arow) << 4));
        if (kc + 8 < NKC) {
            const int col = ((kc + 8) << 5) + ko;
            p0[sl] = *(const bf16x8*)((col < len0) ? (b00 + col) : (b10 + (col - len0)));
            p1[sl] = *(const bf16x8*)((col < len0) ? (b01 + col) : (b11 + (col - len0)));
        }
        acc[0][0] = __builtin_amdgcn_mfma_f32_16x16x32_bf16(fa0, fb0, acc[0][0], 0, 0, 0);
        acc[0][1] = __builtin_amdgcn_mfma_f32_16x16x32_bf16(fa0, fb1, acc[0][1], 0, 0, 0);
        acc[1][0] = __builtin_amdgcn_mfma_f32_16x16x32_bf16(fa1, fb0, acc[1][0], 0, 0, 0);
        acc[1][1] = __builtin_amdgcn_mfma_f32_16x16x32_bf16(fa1, fb1, acc[1][1], 0, 0, 0);
    }
}

// Wave-private LSTM epilogue: 32(m) x 32(n'=8u x 4gate) tile via per-wave 4KB LDS scratch.
__device__ __forceinline__ void cell_epi_w(
    char* scrw, f32x4 acc[2][2], int mrow, int np0, const float* bias_p,
    float* c, const float* mask_h, const float* mask_c,
    short* h2_out, short* h2_aux, const float* mask_aux)
{
    const int lane = threadIdx.x & 63;
#pragma unroll
    for (int mi = 0; mi < 2; ++mi)
#pragma unroll
        for (int ni = 0; ni < 2; ++ni) {
            const int row = mi * 16 + ((lane >> 4) << 2);
            const int col = ni * 16 + (lane & 15);
#pragma unroll
            for (int r = 0; r < 4; ++r)
                *(float*)(scrw + (row + r) * 128 + (col << 2)) = acc[mi][ni][r];
        }
    asm volatile("s_waitcnt lgkmcnt(0)" ::: "memory");
    const int ul = lane & 7;
    const int u  = (np0 >> 2) + ul;
    const float4 bs = *(const float4*)(bias_p + np0 + (ul << 2));
#pragma unroll
    for (int r = 0; r < 4; ++r) {
        const int m = ((lane >> 3) << 2) + r;
        const int b = mrow + m;
        f32x4 gv = *(const f32x4*)(scrw + m * 128 + (ul << 4));
        const float gi = gv[0] + bs.x, gf = gv[1] + bs.y, gg = gv[2] + bs.z, go = gv[3] + bs.w;
        const size_t idx = (size_t)b * HID + u;
        const float cv = c[idx];
        const float cn = sigf(gf) * cv + sigf(gi) * tanhf(gg);
        const float h  = sigf(go) * tanhf(cn);
        c[idx] = mask_c ? cn * mask_c[idx] : cn;
        const float hm = mask_h ? h * mask_h[idx] : h;
        const short hh = f2bf(hm);
        h2_out[(size_t)b * 1024 + u] = hh;
        h2_out[(size_t)b * 1024 + HID + u] = f2bf(hm - bf2f(hh));
        if (h2_aux) {
            const float ha = h * mask_aux[idx];
            const short ah = f2bf(ha);
            h2_aux[(size_t)b * 1024 + u] = ah;
            h2_aux[(size_t)b * 1024 + HID + u] = f2bf(ha - bf2f(ah));
        }
    }
}

// 128(m) x 32(n) projection, LDS-staged (block-wide, only on 16 proj blocks)
__device__ void proj_phase(char* scr, const short* A, const short* Wp2,
                           int m0, int n0, float* dst, const float* bp)
{
    const int tid = threadIdx.x, w = tid >> 6, lane = tid & 63, wm = w >> 1, wn = w & 1;
    const int arow = lane & 15, akg = lane >> 4;
    auto stg = [&](int kc, char* d) {
        const int kb = kc << 5;
        { int s = w * 64 + lane; int gg = s >> 7, r = s & 127;
          async16(A + (size_t)(m0 + r) * 1024 + kb + gg * 8, d + s * 16); }
        if (w < 2) { int s = w * 64 + lane; int gg = s >> 5, r = s & 31;
          async16(Wp2 + (size_t)(n0 + r) * 1024 + kb + gg * 8, d + 8192 + s * 16); }
    };
    f32x4 acc[2]; acc[0] = (f32x4){0,0,0,0}; acc[1] = (f32x4){0,0,0,0};
    stg(0, scr);
    __syncthreads();
    for (int kc = 0; kc < 32; ++kc) {
        char* cur = scr + (kc & 1) * 10240;
        if (kc + 1 < 32) stg(kc + 1, scr + ((kc & 1) ^ 1) * 10240);
        bf16x8 fb = *(const bf16x8*)(cur + 8192 + akg * 512 + (wn * 16 + arow) * 16);
        bf16x8 fa[2];
#pragma unroll
        for (int mi = 0; mi < 2; ++mi)
            fa[mi] = *(const bf16x8*)(cur + akg * 2048 + (wm * 32 + mi * 16 + arow) * 16);
#pragma unroll
        for (int mi = 0; mi < 2; ++mi)
            acc[mi] = __builtin_amdgcn_mfma_f32_16x16x32_bf16(fa[mi], fb, acc[mi], 0, 0, 0);
        __syncthreads();
    }
    const int col = wn * 16 + (lane & 15);
#pragma unroll
    for (int mi = 0; mi < 2; ++mi) {
        int rowb = wm * 32 + mi * 16 + (lane >> 4) * 4;
#pragma unroll
        for (int r = 0; r < 4; ++r) {
            int m = rowb + r;
            *(float*)(scr + m * 128 + (((col >> 2) ^ (m & 7)) << 4) + ((col & 3) << 2)) = acc[mi][r];
        }
    }
    __syncthreads();
    const int nl = tid & 31, mb = (tid >> 5) * 8;
    const float bb = bp[n0 + nl];
#pragma unroll
    for (int q = 0; q < 8; ++q) {
        int m = mb + q;
        float v = *(float*)(scr + m * 128 + (((nl >> 2) ^ (m & 7)) << 4) + ((nl & 3) << 2));
        dst[(size_t)(m0 + m) * NIN + n0 + nl] = v + bb;
    }
    __syncthreads();
}

// ---------------- persistent kernels ----------------

__global__ void __launch_bounds__(512, 2) enc_kernel(
    const short* __restrict__ X2, const short* __restrict__ W0, const short* __restrict__ W1,
    short* hA0s, short* hA1s, short* hB0s, short* hB1s, short* hd0s, short* hd1s,
    float* cA, float* cB,
    const float* __restrict__ bias0, const float* __restrict__ bias1,
    const float* __restrict__ enc_mask, unsigned* bar)
{
    extern __shared__ __align__(16) char lds[];
    const int bid = blockIdx.x;
    const int half = bid >> 7, hb = bid & 127;
    const int m0 = (hb & 1) * 256, np0 = (hb >> 1) * 32;
    const int K = half ? 2048 : 1280;
    const short* W = half ? W1 : W0;
    load_wres(lds, W + (size_t)np0 * K, K);
    char* scr = lds + (size_t)K * 64;
    const int w = threadIdx.x >> 6;
    char* scrw = scr + (w << 12);
    const int mrow = m0 + (w << 5);
    __syncthreads();
    unsigned ep = 0;
    for (int tt = 0; tt <= TST; ++tt) {
        const bool act = half ? (tt >= 1) : (tt < TST);
        if (act) {
            const int t = half ? tt - 1 : tt;
            f32x4 acc[2][2];
#pragma unroll
            for (int a = 0; a < 2; ++a)
#pragma unroll
                for (int b2 = 0; b2 < 2; ++b2) acc[a][b2] = (f32x4){0.f, 0.f, 0.f, 0.f};
            if (half) {
                gemm_regA<64>(lds, (t & 1) ? hd1s : hd0s, 1024, 1024,
                              (t & 1) ? hB1s : hB0s, 1024, mrow, acc);
                cell_epi_w(scrw, acc, mrow, np0, bias1, cB, nullptr, nullptr,
                           (t & 1) ? hB0s : hB1s, nullptr, nullptr);
            } else {
                gemm_regA<40>(lds, X2 + (size_t)t * BAT * 256, 256, 256,
                              (t & 1) ? hA1s : hA0s, 1024, mrow, acc);
                cell_epi_w(scrw, acc, mrow, np0, bias0, cA, nullptr, nullptr,
                           (t & 1) ? hA0s : hA1s,
                           (t & 1) ? hd1s : hd0s, enc_mask + (size_t)t * SBZ);
            }
        }
        gbar2(bar, bid, ++ep);
    }
}

__global__ void __launch_bounds__(512, 2) dec_kernel(
    const short* __restrict__ Wd1, const short* __restrict__ Wd2, const short* __restrict__ W2p,
    short* hA0s, short* hA1s, short* hB0s, short* hB1s,
    float* cA, float* cB,
    const float* __restrict__ bias_d1, const float* __restrict__ bias_d2,
    const float* __restrict__ dec_h_mask, const float* __restrict__ dec_c_mask,
    const float* __restrict__ bp, float* pred_all, unsigned* bar)
{
    extern __shared__ __align__(16) char lds[];
    const int bid = blockIdx.x, half = bid >> 7, hb = bid & 127;
    const int m0 = (hb & 1) * 256, np0 = (hb >> 1) * 32;
    const short* Wres = half ? Wd2 : Wd1;
    load_wres(lds, Wres + (size_t)np0 * 2048, 2048);
    char* scr = lds + 131072;
    const int w = threadIdx.x >> 6;
    char* scrw = scr + (w << 12);
    const int mrow = m0 + (w << 5);
    const bool pj = (half == 1) && (hb < 16);
    const int m0p = (hb & 3) * 128, n0p = (hb >> 2) * 32;
    __syncthreads();
    unsigned ep = 0;
    for (int s = 0; s < HOR - 1; ++s) {
        const short* hAc = (s & 1) ? hA1s : hA0s;
        short*       hAn = (s & 1) ? hA0s : hA1s;
        const short* hBc = (s & 1) ? hB1s : hB0s;
        short*       hBn = (s & 1) ? hB0s : hB1s;
        if (half == 0) {
            f32x4 acc[2][2];
#pragma unroll
            for (int a = 0; a < 2; ++a)
#pragma unroll
                for (int b2 = 0; b2 < 2; ++b2) acc[a][b2] = (f32x4){0.f, 0.f, 0.f, 0.f};
            gemm_regA<64>(lds, hBc, 1024, 1024, hAc, 1024, mrow, acc);
            cell_epi_w(scrw, acc, mrow, np0, bias_d1, cA,
                       dec_h_mask + (size_t)s * SBZ, dec_c_mask + (size_t)s * SBZ,
                       hAn, nullptr, nullptr);
        } else if (pj) {
            proj_phase(scr, hBc, W2p, m0p, n0p, pred_all + (size_t)s * BAT * NIN, bp);
        }
        gbar2(bar, bid, ++ep);
        if (half == 1) {
            f32x4 acc[2][2];
#pragma unroll
            for (int a = 0; a < 2; ++a)
#pragma unroll
                for (int b2 = 0; b2 < 2; ++b2) acc[a][b2] = (f32x4){0.f, 0.f, 0.f, 0.f};
            gemm_regA<64>(lds, hAn, 1024, 1024, hBc, 1024, mrow, acc);
            cell_epi_w(scrw, acc, mrow, np0, bias_d2, cB, nullptr, nullptr,
                       hBn, nullptr, nullptr);
        }
        gbar2(bar, bid, ++ep);
    }
    if (pj) proj_phase(scr, hB1s, W2p, m0p, n0p, pred_all + (size_t)(HOR - 1) * BAT * NIN, bp);
}

__global__ __launch_bounds__(256) void transpose_out(const float* __restrict__ pred_all,
                                                     float* __restrict__ out) {
    __shared__ float tl[32][65];
    const int base = blockIdx.x * 64;
    const int tid = threadIdx.x;
    for (int i = tid; i < 32 * 64; i += 256) {
        int s = i >> 6, f = i & 63;
        tl[s][f] = pred_all[(size_t)s * (BAT * NIN) + base + f];
    }
    __syncthreads();
    for (int i = tid; i < 64 * 32; i += 256) {
        int f = i >> 5, s = i & 31;
        out[(size_t)(base + f) * HOR + s] = tl[s][f];
    }
}

// ---------------- host ----------------

extern "C" void kernel_launch(void* const* d_in, const int* in_sizes, int n_in,
                              void* d_out, int out_size, void* d_ws, size_t ws_size,
                              hipStream_t stream) {
    (void)in_sizes; (void)n_in; (void)out_size; (void)ws_size;
    const float* window = (const float*)d_in[0];
    const float* Wih0 = (const float*)d_in[1];
    const float* Whh0 = (const float*)d_in[2];
    const float* bih0 = (const float*)d_in[3];
    const float* bhh0 = (const float*)d_in[4];
    const float* Wih1 = (const float*)d_in[5];
    const float* Whh1 = (const float*)d_in[6];
    const float* bih1 = (const float*)d_in[7];
    const float* bhh1 = (const float*)d_in[8];
    const float* Wc1i = (const float*)d_in[9];
    const float* Wc1h = (const float*)d_in[10];
    const float* bc1i = (const float*)d_in[11];
    const float* bc1h = (const float*)d_in[12];
    const float* Wc2i = (const float*)d_in[13];
    const float* Wc2h = (const float*)d_in[14];
    const float* bc2i = (const float*)d_in[15];
    const float* bc2h = (const float*)d_in[16];
    const float* Wp   = (const float*)d_in[17];
    const float* bp   = (const float*)d_in[18];
    const float* enc_mask   = (const float*)d_in[19];
    const float* dec_h_mask = (const float*)d_in[20];
    const float* dec_c_mask = (const float*)d_in[21];
    float* out = (float*)d_out;

    char* base = (char*)d_ws;
    size_t off = 0;
    auto take = [&](size_t bytes) -> char* {
        off = (off + 255) & ~(size_t)255;
        char* r = base + off; off += bytes; return r;
    };
    short* W2e0 = (short*)take((size_t)2048 * 1280 * 2);
    short* W2e1 = (short*)take((size_t)2048 * 2048 * 2);
    short* W2d1 = (short*)take((size_t)2048 * 2048 * 2);   // fused [Wfuse|Wc1h] hi/lo
    short* W2d2 = (short*)take((size_t)2048 * 2048 * 2);
    short* W2p  = (short*)take((size_t)128 * 1024 * 2);
    float* Wfuse = (float*)take((size_t)2048 * 512 * 4);
    float* badd  = (float*)take((size_t)2048 * 4);
    float* bias0 = (float*)take((size_t)2048 * 4);
    float* bias1 = (float*)take((size_t)2048 * 4);
    float* biasd1 = (float*)take((size_t)2048 * 4);
    float* biasd2 = (float*)take((size_t)2048 * 4);
    short* hA2[2] = {(short*)take((size_t)BAT * 1024 * 2), (short*)take((size_t)BAT * 1024 * 2)};
    short* hB2[2] = {(short*)take((size_t)BAT * 1024 * 2), (short*)take((size_t)BAT * 1024 * 2)};
    short* hd2[2] = {(short*)take((size_t)BAT * 1024 * 2), (short*)take((size_t)BAT * 1024 * 2)};
    float* cA = (float*)take(SBZ * 4);
    float* cB = (float*)take(SBZ * 4);
    float* pred_all = (float*)take((size_t)HOR * BAT * NIN * 4);
    unsigned* bars = (unsigned*)take(16384);   // enc bar @ 0, dec bar @ +2048 u32 (8KB)
    short* X2 = (short*)take((size_t)TST * BAT * 256 * 2);

    // prep (re-done every call; deterministic)
    prep_fuse<<<(2048 * 512 + 255) / 256, 256, 0, stream>>>(Wc1i, Wp, Wfuse);
    prep_badd<<<8, 256, 0, stream>>>(Wc1i, bp, badd);
    prep_wp<<<(128 * 1024 + 255) / 256, 256, 0, stream>>>(Wp, W2p);
    prep_w<<<(2048 * 1280 + 255) / 256, 256, 0, stream>>>(Wih0, Whh0, W2e0, NIN, 1280);
    prep_w<<<(2048 * 2048 + 255) / 256, 256, 0, stream>>>(Wih1, Whh1, W2e1, HID, 2048);
    prep_w<<<(2048 * 2048 + 255) / 256, 256, 0, stream>>>(Wfuse, Wc1h, W2d1, HID, 2048);
    prep_w<<<(2048 * 2048 + 255) / 256, 256, 0, stream>>>(Wc2i, Wc2h, W2d2, HID, 2048);
    prep_bias<<<8, 256, 0, stream>>>(bih0, bhh0, nullptr, bias0);
    prep_bias<<<8, 256, 0, stream>>>(bih1, bhh1, nullptr, bias1);
    prep_bias<<<8, 256, 0, stream>>>(bc1i, bc1h, badd, biasd1);
    prep_bias<<<8, 256, 0, stream>>>(bc2i, bc2h, nullptr, biasd2);
    prep_x<<<(int)(((size_t)TST * BAT * NIN + 255) / 256), 256, 0, stream>>>(window, X2);
    hipMemsetAsync(hA2[0], 0, (size_t)BAT * 1024 * 2, stream);
    hipMemsetAsync(hB2[0], 0, (size_t)BAT * 1024 * 2, stream);
    hipMemsetAsync(cA, 0, SBZ * 4, stream);
    hipMemsetAsync(cB, 0, SBZ * 4, stream);
    hipMemsetAsync(bars, 0, 16384, stream);

    hipFuncSetAttribute((const void*)enc_kernel, hipFuncAttributeMaxDynamicSharedMemorySize, 163840);
    hipFuncSetAttribute((const void*)dec_kernel, hipFuncAttributeMaxDynamicSharedMemorySize, 163840);

    enc_kernel<<<256, 512, 163840, stream>>>(
        X2, W2e0, W2e1,
        hA2[0], hA2[1], hB2[0], hB2[1], hd2[0], hd2[1],
        cA, cB, bias0, bias1, enc_mask, bars);

    dec_kernel<<<256, 512, 163840, stream>>>(
        W2d1, W2d2, W2p,
        hA2[0], hA2[1], hB2[0], hB2[1],
        cA, cB, biasd1, biasd2, dec_h_mask, dec_c_mask,
        bp, pred_all, bars + 2048);

    transpose_out<<<(BAT * NIN) / 64, 256, 0, stream>>>(pred_all, out);
}

// Round 8
// 8140.908 us; speedup vs baseline: 2.3527x; 1.1114x over previous
//
#include <hip/hip_runtime.h>
#include <math.h>

#define HID 512
#define BAT 512
#define NIN 128
#define TST 128
#define HOR 32
#define SBZ ((size_t)BAT * HID)

using bf16x8 = __attribute__((ext_vector_type(8))) __bf16;
using f32x4  = __attribute__((ext_vector_type(4))) float;

__device__ __forceinline__ float sigf(float x) { return 1.0f / (1.0f + expf(-x)); }

__device__ __forceinline__ short f2bf(float x) {
    union { float f; unsigned u; } v; v.f = x;
    unsigned r = (v.u + 0x7FFFu + ((v.u >> 16) & 1u)) >> 16;
    return (short)r;
}
__device__ __forceinline__ float bf2f(short s) {
    union { unsigned u; float f; } v; v.u = ((unsigned)(unsigned short)s) << 16;
    return v.f;
}
__device__ __forceinline__ bf16x8 asbf(f32x4 v) {
    union { f32x4 f; bf16x8 b; } u; u.f = v; return u.b;
}
__device__ __forceinline__ void async16(const void* g, void* l) {
    __builtin_amdgcn_global_load_lds(
        (const __attribute__((address_space(1))) void*)g,
        (__attribute__((address_space(3))) void*)l, 16, 0, 0);
}

// hierarchical grid barrier; flag at system scope (fresh loads, no stale-L2 outlier)
__device__ __forceinline__ void gbar2(unsigned* bar, int bid, unsigned ep) {
    __syncthreads();
    if (threadIdx.x == 0) {
        unsigned* leaf = bar + ((unsigned)bid >> 3) * 32;
        unsigned* root = bar + 1024;
        unsigned* flag = bar + 1056;
        unsigned old = __hip_atomic_fetch_add(leaf, 1u, __ATOMIC_RELEASE, __HIP_MEMORY_SCOPE_AGENT);
        if (old == 8u * ep - 1u) {
            unsigned ro = __hip_atomic_fetch_add(root, 1u, __ATOMIC_RELEASE, __HIP_MEMORY_SCOPE_AGENT);
            if (ro == 32u * ep - 1u)
                __hip_atomic_store(flag, ep, __ATOMIC_RELEASE, __HIP_MEMORY_SCOPE_SYSTEM);
        }
        int spin = 0;
        while (__hip_atomic_load(flag, __ATOMIC_RELAXED, __HIP_MEMORY_SCOPE_SYSTEM) < ep) {
            __builtin_amdgcn_s_sleep(1);
            if (((++spin) & 63) == 0)
                __hip_atomic_fetch_add(flag, 0u, __ATOMIC_RELAXED, __HIP_MEMORY_SCOPE_AGENT);
        }
        __builtin_amdgcn_fence(__ATOMIC_ACQUIRE, "agent");
    }
    __syncthreads();
}

// ---------------- prep kernels ----------------

__global__ __launch_bounds__(256) void prep_w(const float* __restrict__ Wih,
                                              const float* __restrict__ Whh,
                                              short* __restrict__ W2, int Kx, int Kp) {
    size_t i = (size_t)blockIdx.x * 256 + threadIdx.x;
    if (i >= (size_t)2048 * Kp) return;
    int np = (int)(i / Kp), kp = (int)(i % Kp);
    int u = np >> 2, gate = np & 3;
    int on = gate * HID + u;
    float w; bool islo = false;
    if (kp < Kx)                { w = Wih[(size_t)on * Kx + kp]; }
    else if (kp < 2 * Kx)       { w = Wih[(size_t)on * Kx + (kp - Kx)]; islo = true; }
    else if (kp < 2 * Kx + HID) { w = Whh[(size_t)on * HID + (kp - 2 * Kx)]; }
    else                        { w = Whh[(size_t)on * HID + (kp - 2 * Kx - HID)]; islo = true; }
    short hi = f2bf(w);
    W2[i] = islo ? f2bf(w - bf2f(hi)) : hi;
}

__global__ __launch_bounds__(256) void prep_x(const float* __restrict__ window,
                                              short* __restrict__ x2) {
    size_t i = (size_t)blockIdx.x * 256 + threadIdx.x;
    if (i >= (size_t)TST * BAT * NIN) return;
    int n = (int)(i & 127);
    int b = (int)((i >> 7) & 511);
    int t = (int)(i >> 16);
    float x = window[(size_t)b * (TST * NIN) + (size_t)t * NIN + n];
    short hi = f2bf(x);
    short* dst = x2 + (size_t)t * (BAT * 256) + (size_t)b * 256;
    dst[n] = hi;
    dst[128 + n] = f2bf(x - bf2f(hi));
}

__global__ __launch_bounds__(256) void prep_fuse(const float* __restrict__ Wc1i,
                                                 const float* __restrict__ Wp,
                                                 float* __restrict__ Wfuse) {
    size_t i = (size_t)blockIdx.x * 256 + threadIdx.x;
    if (i >= (size_t)2048 * 512) return;
    int on = (int)(i >> 9), k = (int)(i & 511);
    float s = 0.f;
    for (int n = 0; n < NIN; ++n) s += Wc1i[(size_t)on * NIN + n] * Wp[(size_t)n * HID + k];
    Wfuse[i] = s;
}

__global__ __launch_bounds__(256) void prep_badd(const float* __restrict__ Wc1i,
                                                 const float* __restrict__ bp,
                                                 float* __restrict__ badd) {
    int on = blockIdx.x * 256 + threadIdx.x;
    if (on >= 2048) return;
    float s = 0.f;
    for (int n = 0; n < NIN; ++n) s += Wc1i[(size_t)on * NIN + n] * bp[n];
    badd[on] = s;
}

__global__ __launch_bounds__(256) void prep_bias(const float* __restrict__ bih,
                                                 const float* __restrict__ bhh,
                                                 const float* __restrict__ badd,
                                                 float* __restrict__ bout) {
    int np = blockIdx.x * 256 + threadIdx.x;
    if (np >= 2048) return;
    int on = (np & 3) * HID + (np >> 2);
    float v = bih[on] + bhh[on];
    if (badd) v += badd[on];
    bout[np] = v;
}

__global__ __launch_bounds__(256) void prep_wp(const float* __restrict__ Wp,
                                               short* __restrict__ W2p) {
    int i = blockIdx.x * 256 + threadIdx.x;
    if (i >= 128 * 1024) return;
    int n = i >> 10, k = i & 1023;
    float w = Wp[(size_t)n * HID + (k & 511)];
    short hi = f2bf(w);
    W2p[i] = (k < 512) ? hi : f2bf(w - bf2f(hi));
}

// ---------------- device building blocks ----------------

// resident W: 32 rows x K, k-major granules: lds[j*512 + r*16]
__device__ __forceinline__ void load_wres(char* lds, const short* Wg, int K) {
    const int tid = threadIdx.x;
    const int r = tid >> 4;
    const int cnt = K >> 7;
    const int jb = (tid & 15) * cnt;
    for (int q = 0; q < cnt; ++q) {
        int j = jb + q;
        bf16x8 v = *(const bf16x8*)(Wg + (size_t)r * K + j * 8);
        *(bf16x8*)(lds + j * 512 + r * 16) = v;
    }
}

// Wave-private GEMM 32(m) x 32(n') over K; A via asm global loads with counted vmcnt
// (depth D=12 pairs in flight); W from resident LDS. No block barriers inside.
template<int NKC>
__device__ __forceinline__ void gemm_pipe(
    const char* wres,
    const short* __restrict__ a0, int lda0, int len0,
    const short* __restrict__ a1, int lda1,
    int mrow, f32x4 acc[2][2])
{
    constexpr int D = 12;
    const int lane = threadIdx.x & 63;
    const int arow = lane & 15, akg = lane >> 4, ko = akg << 3;
    const short* b00 = a0 + (size_t)(mrow + arow) * lda0;
    const short* b01 = a0 + (size_t)(mrow + 16 + arow) * lda0;
    const short* b10 = a1 + (size_t)(mrow + arow) * lda1;
    const short* b11 = a1 + (size_t)(mrow + 16 + arow) * lda1;

    f32x4 q0[D], q1[D];
#pragma unroll
    for (int i = 0; i < D; ++i) {
        const int col = (i << 5) + ko;
        const short* s0 = (col < len0) ? (b00 + col) : (b10 + (col - len0));
        const short* s1 = (col < len0) ? (b01 + col) : (b11 + (col - len0));
        asm volatile("global_load_dwordx4 %0, %1, off" : "=v"(q0[i]) : "v"(s0));
        asm volatile("global_load_dwordx4 %0, %1, off" : "=v"(q1[i]) : "v"(s1));
    }
#pragma unroll
    for (int kc = 0; kc < NKC; ++kc) {
        const int sl = kc % D;
        // oldest pair must be complete; outstanding after = 2*min(D, NKC-kc) - 2
        asm volatile("s_waitcnt vmcnt(%2)"
                     : "+v"(q0[sl]), "+v"(q1[sl])
                     : "i"((2 * ((NKC - kc) < D ? (NKC - kc) : D)) - 2));
        const bf16x8 fa0 = asbf(q0[sl]);
        const bf16x8 fa1 = asbf(q1[sl]);
        if (kc + D < NKC) {
            const int col = ((kc + D) << 5) + ko;
            const short* s0 = (col < len0) ? (b00 + col) : (b10 + (col - len0));
            const short* s1 = (col < len0) ? (b01 + col) : (b11 + (col - len0));
            asm volatile("global_load_dwordx4 %0, %1, off" : "=v"(q0[sl]) : "v"(s0));
            asm volatile("global_load_dwordx4 %0, %1, off" : "=v"(q1[sl]) : "v"(s1));
        }
        const char* wrow = wres + (size_t)(((kc << 2) + akg) << 9);
        const bf16x8 fb0 = *(const bf16x8*)(wrow + (arow << 4));
        const bf16x8 fb1 = *(const bf16x8*)(wrow + ((16 + arow) << 4));
        acc[0][0] = __builtin_amdgcn_mfma_f32_16x16x32_bf16(fa0, fb0, acc[0][0], 0, 0, 0);
        acc[0][1] = __builtin_amdgcn_mfma_f32_16x16x32_bf16(fa0, fb1, acc[0][1], 0, 0, 0);
        acc[1][0] = __builtin_amdgcn_mfma_f32_16x16x32_bf16(fa1, fb0, acc[1][0], 0, 0, 0);
        acc[1][1] = __builtin_amdgcn_mfma_f32_16x16x32_bf16(fa1, fb1, acc[1][1], 0, 0, 0);
    }
    asm volatile("s_waitcnt vmcnt(0)");
}

// Wave-private LSTM epilogue; c-state in registers (block/lane-private, epoch-invariant map)
__device__ __forceinline__ void cell_epi_r(
    char* scrw, f32x4 acc[2][2], float creg[4], int mrow, int np0, const float* bias_p,
    const float* mask_h, const float* mask_c,
    short* h2_out, short* h2_aux, const float* mask_aux)
{
    const int lane = threadIdx.x & 63;
#pragma unroll
    for (int mi = 0; mi < 2; ++mi)
#pragma unroll
        for (int ni = 0; ni < 2; ++ni) {
            const int row = mi * 16 + ((lane >> 4) << 2);
            const int col = ni * 16 + (lane & 15);
#pragma unroll
            for (int r = 0; r < 4; ++r)
                *(float*)(scrw + (row + r) * 128 + (col << 2)) = acc[mi][ni][r];
        }
    asm volatile("s_waitcnt lgkmcnt(0)" ::: "memory");
    const int ul = lane & 7;
    const int u  = (np0 >> 2) + ul;
    const float4 bs = *(const float4*)(bias_p + np0 + (ul << 2));
#pragma unroll
    for (int r = 0; r < 4; ++r) {
        const int m = ((lane >> 3) << 2) + r;
        const int b = mrow + m;
        f32x4 gv = *(const f32x4*)(scrw + m * 128 + (ul << 4));
        const float gi = gv[0] + bs.x, gf = gv[1] + bs.y, gg = gv[2] + bs.z, go = gv[3] + bs.w;
        const size_t idx = (size_t)b * HID + u;
        const float cn = sigf(gf) * creg[r] + sigf(gi) * tanhf(gg);
        const float h  = sigf(go) * tanhf(cn);
        creg[r] = mask_c ? cn * mask_c[idx] : cn;
        const float hm = mask_h ? h * mask_h[idx] : h;
        const short hh = f2bf(hm);
        h2_out[(size_t)b * 1024 + u] = hh;
        h2_out[(size_t)b * 1024 + HID + u] = f2bf(hm - bf2f(hh));
        if (h2_aux) {
            const float ha = h * mask_aux[idx];
            const short ah = f2bf(ha);
            h2_aux[(size_t)b * 1024 + u] = ah;
            h2_aux[(size_t)b * 1024 + HID + u] = f2bf(ha - bf2f(ah));
        }
    }
}

// 128(m) x 32(n) projection, LDS-staged (block-wide, only on 16 proj blocks)
__device__ void proj_phase(char* scr, const short* A, const short* Wp2,
                           int m0, int n0, float* dst, const float* bp)
{
    const int tid = threadIdx.x, w = tid >> 6, lane = tid & 63, wm = w >> 1, wn = w & 1;
    const int arow = lane & 15, akg = lane >> 4;
    auto stg = [&](int kc, char* d) {
        const int kb = kc << 5;
        { int s = w * 64 + lane; int gg = s >> 7, r = s & 127;
          async16(A + (size_t)(m0 + r) * 1024 + kb + gg * 8, d + s * 16); }
        if (w < 2) { int s = w * 64 + lane; int gg = s >> 5, r = s & 31;
          async16(Wp2 + (size_t)(n0 + r) * 1024 + kb + gg * 8, d + 8192 + s * 16); }
    };
    f32x4 acc[2]; acc[0] = (f32x4){0,0,0,0}; acc[1] = (f32x4){0,0,0,0};
    stg(0, scr);
    __syncthreads();
    for (int kc = 0; kc < 32; ++kc) {
        char* cur = scr + (kc & 1) * 10240;
        if (kc + 1 < 32) stg(kc + 1, scr + ((kc & 1) ^ 1) * 10240);
        bf16x8 fb = *(const bf16x8*)(cur + 8192 + akg * 512 + (wn * 16 + arow) * 16);
        bf16x8 fa[2];
#pragma unroll
        for (int mi = 0; mi < 2; ++mi)
            fa[mi] = *(const bf16x8*)(cur + akg * 2048 + (wm * 32 + mi * 16 + arow) * 16);
#pragma unroll
        for (int mi = 0; mi < 2; ++mi)
            acc[mi] = __builtin_amdgcn_mfma_f32_16x16x32_bf16(fa[mi], fb, acc[mi], 0, 0, 0);
        __syncthreads();
    }
    const int col = wn * 16 + (lane & 15);
#pragma unroll
    for (int mi = 0; mi < 2; ++mi) {
        int rowb = wm * 32 + mi * 16 + (lane >> 4) * 4;
#pragma unroll
        for (int r = 0; r < 4; ++r) {
            int m = rowb + r;
            *(float*)(scr + m * 128 + (((col >> 2) ^ (m & 7)) << 4) + ((col & 3) << 2)) = acc[mi][r];
        }
    }
    __syncthreads();
    const int nl = tid & 31, mb = (tid >> 5) * 8;
    const float bb = bp[n0 + nl];
#pragma unroll
    for (int q = 0; q < 8; ++q) {
        int m = mb + q;
        float v = *(float*)(scr + m * 128 + (((nl >> 2) ^ (m & 7)) << 4) + ((nl & 3) << 2));
        dst[(size_t)(m0 + m) * NIN + n0 + nl] = v + bb;
    }
    __syncthreads();
}

// ---------------- single persistent kernel (enc + dec) ----------------

__global__ void __launch_bounds__(512, 2) persist_kernel(
    const short* __restrict__ X2,
    const short* __restrict__ W0, const short* __restrict__ W1,
    const short* __restrict__ Wd1, const short* __restrict__ Wd2,
    const short* __restrict__ W2p,
    short* hA0s, short* hA1s, short* hB0s, short* hB1s, short* hd0s, short* hd1s,
    const float* __restrict__ bias0, const float* __restrict__ bias1,
    const float* __restrict__ biasd1, const float* __restrict__ biasd2,
    const float* __restrict__ enc_mask, const float* __restrict__ dec_h_mask,
    const float* __restrict__ dec_c_mask,
    const float* __restrict__ bp, float* pred_all, unsigned* bar)
{
    extern __shared__ __align__(16) char lds[];
    const int bid = blockIdx.x, half = bid >> 7, hb = bid & 127;
    const int m0 = (hb & 1) * 256, np0 = (hb >> 1) * 32;
    const int w = threadIdx.x >> 6;
    char* scr  = lds + 131072;
    char* scrw = scr + (w << 12);
    const int mrow = m0 + (w << 5);
    float creg[4] = {0.f, 0.f, 0.f, 0.f};   // half0: cA slice, half1: cB slice

    // ---- encoder phase ----
    {
        const int K = half ? 2048 : 1280;
        load_wres(lds, (half ? W1 : W0) + (size_t)np0 * K, K);
    }
    __syncthreads();
    unsigned ep = 0;
    for (int tt = 0; tt <= TST; ++tt) {
        const bool act = half ? (tt >= 1) : (tt < TST);
        if (act) {
            const int t = half ? tt - 1 : tt;
            f32x4 acc[2][2];
#pragma unroll
            for (int a = 0; a < 2; ++a)
#pragma unroll
                for (int b2 = 0; b2 < 2; ++b2) acc[a][b2] = (f32x4){0.f, 0.f, 0.f, 0.f};
            if (half) {
                gemm_pipe<64>(lds, (t & 1) ? hd1s : hd0s, 1024, 1024,
                              (t & 1) ? hB1s : hB0s, 1024, mrow, acc);
                cell_epi_r(scrw, acc, creg, mrow, np0, bias1, nullptr, nullptr,
                           (t & 1) ? hB0s : hB1s, nullptr, nullptr);
            } else {
                gemm_pipe<40>(lds, X2 + (size_t)t * BAT * 256, 256, 256,
                              (t & 1) ? hA1s : hA0s, 1024, mrow, acc);
                cell_epi_r(scrw, acc, creg, mrow, np0, bias0, nullptr, nullptr,
                           (t & 1) ? hA0s : hA1s,
                           (t & 1) ? hd1s : hd0s, enc_mask + (size_t)t * SBZ);
            }
        }
        gbar2(bar, bid, ++ep);
    }

    // ---- decoder phase: reload resident W (LDS is block-private) ----
    load_wres(lds, (half ? Wd2 : Wd1) + (size_t)np0 * 2048, 2048);
    __syncthreads();
    const bool pj = (half == 1) && (hb < 16);
    const int m0p = (hb & 3) * 128, n0p = (hb >> 2) * 32;
    for (int s = 0; s < HOR - 1; ++s) {
        const short* hAc = (s & 1) ? hA1s : hA0s;
        short*       hAn = (s & 1) ? hA0s : hA1s;
        const short* hBc = (s & 1) ? hB1s : hB0s;
        short*       hBn = (s & 1) ? hB0s : hB1s;
        if (half == 0) {
            f32x4 acc[2][2];
#pragma unroll
            for (int a = 0; a < 2; ++a)
#pragma unroll
                for (int b2 = 0; b2 < 2; ++b2) acc[a][b2] = (f32x4){0.f, 0.f, 0.f, 0.f};
            gemm_pipe<64>(lds, hBc, 1024, 1024, hAc, 1024, mrow, acc);
            cell_epi_r(scrw, acc, creg, mrow, np0, biasd1,
                       dec_h_mask + (size_t)s * SBZ, dec_c_mask + (size_t)s * SBZ,
                       hAn, nullptr, nullptr);
        } else if (pj) {
            proj_phase(scr, hBc, W2p, m0p, n0p, pred_all + (size_t)s * BAT * NIN, bp);
        }
        gbar2(bar, bid, ++ep);
        if (half == 1) {
            f32x4 acc[2][2];
#pragma unroll
            for (int a = 0; a < 2; ++a)
#pragma unroll
                for (int b2 = 0; b2 < 2; ++b2) acc[a][b2] = (f32x4){0.f, 0.f, 0.f, 0.f};
            gemm_pipe<64>(lds, hAn, 1024, 1024, hBc, 1024, mrow, acc);
            cell_epi_r(scrw, acc, creg, mrow, np0, biasd2, nullptr, nullptr,
                       hBn, nullptr, nullptr);
        }
        gbar2(bar, bid, ++ep);
    }
    if (pj) proj_phase(scr, hB1s, W2p, m0p, n0p, pred_all + (size_t)(HOR - 1) * BAT * NIN, bp);
}

__global__ __launch_bounds__(256) void transpose_out(const float* __restrict__ pred_all,
                                                     float* __restrict__ out) {
    __shared__ float tl[32][65];
    const int base = blockIdx.x * 64;
    const int tid = threadIdx.x;
    for (int i = tid; i < 32 * 64; i += 256) {
        int s = i >> 6, f = i & 63;
        tl[s][f] = pred_all[(size_t)s * (BAT * NIN) + base + f];
    }
    __syncthreads();
    for (int i = tid; i < 64 * 32; i += 256) {
        int f = i >> 5, s = i & 31;
        out[(size_t)(base + f) * HOR + s] = tl[s][f];
    }
}

// ---------------- host ----------------

extern "C" void kernel_launch(void* const* d_in, const int* in_sizes, int n_in,
                              void* d_out, int out_size, void* d_ws, size_t ws_size,
                              hipStream_t stream) {
    (void)in_sizes; (void)n_in; (void)out_size; (void)ws_size;
    const float* window = (const float*)d_in[0];
    const float* Wih0 = (const float*)d_in[1];
    const float* Whh0 = (const float*)d_in[2];
    const float* bih0 = (const float*)d_in[3];
    const float* bhh0 = (const float*)d_in[4];
    const float* Wih1 = (const float*)d_in[5];
    const float* Whh1 = (const float*)d_in[6];
    const float* bih1 = (const float*)d_in[7];
    const float* bhh1 = (const float*)d_in[8];
    const float* Wc1i = (const float*)d_in[9];
    const float* Wc1h = (const float*)d_in[10];
    const float* bc1i = (const float*)d_in[11];
    const float* bc1h = (const float*)d_in[12];
    const float* Wc2i = (const float*)d_in[13];
    const float* Wc2h = (const float*)d_in[14];
    const float* bc2i = (const float*)d_in[15];
    const float* bc2h = (const float*)d_in[16];
    const float* Wp   = (const float*)d_in[17];
    const float* bp   = (const float*)d_in[18];
    const float* enc_mask   = (const float*)d_in[19];
    const float* dec_h_mask = (const float*)d_in[20];
    const float* dec_c_mask = (const float*)d_in[21];
    float* out = (float*)d_out;

    char* base = (char*)d_ws;
    size_t off = 0;
    auto take = [&](size_t bytes) -> char* {
        off = (off + 255) & ~(size_t)255;
        char* r = base + off; off += bytes; return r;
    };
    short* W2e0 = (short*)take((size_t)2048 * 1280 * 2);
    short* W2e1 = (short*)take((size_t)2048 * 2048 * 2);
    short* W2d1 = (short*)take((size_t)2048 * 2048 * 2);   // fused [Wfuse|Wc1h] hi/lo
    short* W2d2 = (short*)take((size_t)2048 * 2048 * 2);
    short* W2p  = (short*)take((size_t)128 * 1024 * 2);
    float* Wfuse = (float*)take((size_t)2048 * 512 * 4);
    float* badd  = (float*)take((size_t)2048 * 4);
    float* bias0 = (float*)take((size_t)2048 * 4);
    float* bias1 = (float*)take((size_t)2048 * 4);
    float* biasd1 = (float*)take((size_t)2048 * 4);
    float* biasd2 = (float*)take((size_t)2048 * 4);
    short* hA2[2] = {(short*)take((size_t)BAT * 1024 * 2), (short*)take((size_t)BAT * 1024 * 2)};
    short* hB2[2] = {(short*)take((size_t)BAT * 1024 * 2), (short*)take((size_t)BAT * 1024 * 2)};
    short* hd2[2] = {(short*)take((size_t)BAT * 1024 * 2), (short*)take((size_t)BAT * 1024 * 2)};
    float* pred_all = (float*)take((size_t)HOR * BAT * NIN * 4);
    unsigned* bars = (unsigned*)take(16384);
    short* X2 = (short*)take((size_t)TST * BAT * 256 * 2);

    // prep (re-done every call; deterministic)
    prep_fuse<<<(2048 * 512 + 255) / 256, 256, 0, stream>>>(Wc1i, Wp, Wfuse);
    prep_badd<<<8, 256, 0, stream>>>(Wc1i, bp, badd);
    prep_wp<<<(128 * 1024 + 255) / 256, 256, 0, stream>>>(Wp, W2p);
    prep_w<<<(2048 * 1280 + 255) / 256, 256, 0, stream>>>(Wih0, Whh0, W2e0, NIN, 1280);
    prep_w<<<(2048 * 2048 + 255) / 256, 256, 0, stream>>>(Wih1, Whh1, W2e1, HID, 2048);
    prep_w<<<(2048 * 2048 + 255) / 256, 256, 0, stream>>>(Wfuse, Wc1h, W2d1, HID, 2048);
    prep_w<<<(2048 * 2048 + 255) / 256, 256, 0, stream>>>(Wc2i, Wc2h, W2d2, HID, 2048);
    prep_bias<<<8, 256, 0, stream>>>(bih0, bhh0, nullptr, bias0);
    prep_bias<<<8, 256, 0, stream>>>(bih1, bhh1, nullptr, bias1);
    prep_bias<<<8, 256, 0, stream>>>(bc1i, bc1h, badd, biasd1);
    prep_bias<<<8, 256, 0, stream>>>(bc2i, bc2h, nullptr, biasd2);
    prep_x<<<(int)(((size_t)TST * BAT * NIN + 255) / 256), 256, 0, stream>>>(window, X2);
    hipMemsetAsync(hA2[0], 0, (size_t)BAT * 1024 * 2, stream);
    hipMemsetAsync(hB2[0], 0, (size_t)BAT * 1024 * 2, stream);
    hipMemsetAsync(bars, 0, 16384, stream);

    hipFuncSetAttribute((const void*)persist_kernel, hipFuncAttributeMaxDynamicSharedMemorySize, 163840);

    persist_kernel<<<256, 512, 163840, stream>>>(
        X2, W2e0, W2e1, W2d1, W2d2, W2p,
        hA2[0], hA2[1], hB2[0], hB2[1], hd2[0], hd2[1],
        bias0, bias1, biasd1, biasd2,
        enc_mask, dec_h_mask, dec_c_mask,
        bp, pred_all, bars);

    transpose_out<<<(BAT * NIN) / 64, 256, 0, stream>>>(pred_all, out);
}

// Round 9
// 4262.910 us; speedup vs baseline: 4.4930x; 1.9097x over previous
//
#include <hip/hip_runtime.h>
#include <math.h>

#define HID 512
#define BAT 512
#define NIN 128
#define TST 128
#define HOR 32
#define SBZ ((size_t)BAT * HID)

using bf16x8 = __attribute__((ext_vector_type(8))) __bf16;
using f32x4  = __attribute__((ext_vector_type(4))) float;

__device__ __forceinline__ float sigf(float x) { return 1.0f / (1.0f + expf(-x)); }

__device__ __forceinline__ short f2bf(float x) {
    union { float f; unsigned u; } v; v.f = x;
    unsigned r = (v.u + 0x7FFFu + ((v.u >> 16) & 1u)) >> 16;
    return (short)r;
}
__device__ __forceinline__ float bf2f(short s) {
    union { unsigned u; float f; } v; v.u = ((unsigned)(unsigned short)s) << 16;
    return v.f;
}
__device__ __forceinline__ bf16x8 asbf(f32x4 v) {
    union { f32x4 f; bf16x8 b; } u; u.f = v; return u.b;
}

// hierarchical grid barrier (r8-verified): leaf(8) -> root(32) -> flag; relaxed polls.
__device__ __forceinline__ void gbar2(unsigned* bar, int bid, unsigned ep) {
    __syncthreads();
    if (threadIdx.x == 0) {
        unsigned* leaf = bar + ((unsigned)bid >> 3) * 32;
        unsigned* root = bar + 1024;
        unsigned* flag = bar + 1056;
        unsigned old = __hip_atomic_fetch_add(leaf, 1u, __ATOMIC_RELEASE, __HIP_MEMORY_SCOPE_AGENT);
        if (old == 8u * ep - 1u) {
            unsigned ro = __hip_atomic_fetch_add(root, 1u, __ATOMIC_RELEASE, __HIP_MEMORY_SCOPE_AGENT);
            if (ro == 32u * ep - 1u)
                __hip_atomic_store(flag, ep, __ATOMIC_RELEASE, __HIP_MEMORY_SCOPE_SYSTEM);
        }
        int spin = 0;
        while (__hip_atomic_load(flag, __ATOMIC_RELAXED, __HIP_MEMORY_SCOPE_SYSTEM) < ep) {
            __builtin_amdgcn_s_sleep(1);
            if (((++spin) & 63) == 0)
                __hip_atomic_fetch_add(flag, 0u, __ATOMIC_RELAXED, __HIP_MEMORY_SCOPE_AGENT);
        }
        __builtin_amdgcn_fence(__ATOMIC_ACQUIRE, "agent");
    }
    __syncthreads();
}

// ---------------- prep kernels ----------------

// permuted weight rows: n' = u*4 + gate; cols [Wih_hi|Wih_lo|Whh_hi|Whh_lo]; row-major [2048][Kp]
__global__ __launch_bounds__(256) void prep_w(const float* __restrict__ Wih,
                                              const float* __restrict__ Whh,
                                              short* __restrict__ W2, int Kx, int Kp) {
    size_t i = (size_t)blockIdx.x * 256 + threadIdx.x;
    if (i >= (size_t)2048 * Kp) return;
    int np = (int)(i / Kp), kp = (int)(i % Kp);
    int u = np >> 2, gate = np & 3;
    int on = gate * HID + u;
    float w; bool islo = false;
    if (kp < Kx)                { w = Wih[(size_t)on * Kx + kp]; }
    else if (kp < 2 * Kx)       { w = Wih[(size_t)on * Kx + (kp - Kx)]; islo = true; }
    else if (kp < 2 * Kx + HID) { w = Whh[(size_t)on * HID + (kp - 2 * Kx)]; }
    else                        { w = Whh[(size_t)on * HID + (kp - 2 * Kx - HID)]; islo = true; }
    short hi = f2bf(w);
    W2[i] = islo ? f2bf(w - bf2f(hi)) : hi;
}

// X2t: per-t chunk layout [mb=16][fh=2][c=8] chunks of 512 shorts; lane-fragment order.
__global__ __launch_bounds__(256) void prep_x(const float* __restrict__ window,
                                              short* __restrict__ X2t) {
    size_t i = (size_t)blockIdx.x * 256 + threadIdx.x;
    if (i >= (size_t)TST * BAT * NIN) return;
    int n = (int)(i & 127);
    int b = (int)((i >> 7) & 511);
    int t = (int)(i >> 16);
    float x = window[(size_t)b * (TST * NIN) + (size_t)t * NIN + n];
    short hi = f2bf(x);
    short lo = f2bf(x - bf2f(hi));
    int mb2 = ((b >> 5) << 1) | ((b >> 4) & 1);
    int l = (b & 15) + (((n >> 3) & 3) << 4);
    int e = n & 7;
    size_t base = (size_t)t * 131072 + ((size_t)(mb2 * 8 + (n >> 5)) << 9) + l * 8 + e;
    X2t[base] = hi;
    X2t[base + 2048] = lo;   // c_lo = c_hi + 4  -> +4*512 shorts
}

__global__ __launch_bounds__(256) void prep_fuse(const float* __restrict__ Wc1i,
                                                 const float* __restrict__ Wp,
                                                 float* __restrict__ Wfuse) {
    size_t i = (size_t)blockIdx.x * 256 + threadIdx.x;
    if (i >= (size_t)2048 * 512) return;
    int on = (int)(i >> 9), k = (int)(i & 511);
    float s = 0.f;
    for (int n = 0; n < NIN; ++n) s += Wc1i[(size_t)on * NIN + n] * Wp[(size_t)n * HID + k];
    Wfuse[i] = s;
}

__global__ __launch_bounds__(256) void prep_badd(const float* __restrict__ Wc1i,
                                                 const float* __restrict__ bp,
                                                 float* __restrict__ badd) {
    int on = blockIdx.x * 256 + threadIdx.x;
    if (on >= 2048) return;
    float s = 0.f;
    for (int n = 0; n < NIN; ++n) s += Wc1i[(size_t)on * NIN + n] * bp[n];
    badd[on] = s;
}

__global__ __launch_bounds__(256) void prep_bias(const float* __restrict__ bih,
                                                 const float* __restrict__ bhh,
                                                 const float* __restrict__ badd,
                                                 float* __restrict__ bout) {
    int np = blockIdx.x * 256 + threadIdx.x;
    if (np >= 2048) return;
    int on = (np & 3) * HID + (np >> 2);
    float v = bih[on] + bhh[on];
    if (badd) v += badd[on];
    bout[np] = v;
}

// W2p row-major [128][1024]: [0,512)=Wp_hi, [512,1024)=Wp_lo
__global__ __launch_bounds__(256) void prep_wp(const float* __restrict__ Wp,
                                               short* __restrict__ W2p) {
    int i = blockIdx.x * 256 + threadIdx.x;
    if (i >= 128 * 1024) return;
    int n = i >> 10, k = i & 1023;
    float w = Wp[(size_t)n * HID + (k & 511)];
    short hi = f2bf(w);
    W2p[i] = (k < 512) ? hi : f2bf(w - bf2f(hi));
}

// ---------------- device building blocks ----------------

// resident W: 32 rows x K, k-major granules: lds[j*512 + r*16]
__device__ __forceinline__ void load_wres(char* lds, const short* Wg, int K) {
    const int tid = threadIdx.x;
    const int r = tid >> 4;
    const int cnt = K >> 7;
    const int jb = (tid & 15) * cnt;
    for (int q = 0; q < cnt; ++q) {
        int j = jb + q;
        bf16x8 v = *(const bf16x8*)(Wg + (size_t)r * K + j * 8);
        *(bf16x8*)(lds + j * 512 + r * 16) = v;
    }
}

// Wave-private GEMM 32(m) x 32(n') over chunked A (contiguous 1KB per load),
// counted-vmcnt pipeline depth D=12; W from resident LDS. No block barriers.
template<int C0, int C1>
__device__ __forceinline__ void gemm_pipeC(
    const char* wres, const short* a0t, const short* a1t,
    int mb, f32x4 acc[2][2])
{
    constexpr int NKC = C0 + C1;
    constexpr int D = 12;
    const int lane = threadIdx.x & 63;
    const int arow = lane & 15, akg = lane >> 4;
    const size_t lb = (size_t)lane << 4;
    const char* base0 = (const char*)a0t;
    const char* base1 = (const char*)a1t;
    auto cptr = [&](int kc, int fh) -> const char* {
        return (kc < C0)
            ? base0 + (((size_t)(mb * 2 + fh) * C0 + kc) << 10) + lb
            : base1 + (((size_t)(mb * 2 + fh) * C1 + (kc - C0)) << 10) + lb;
    };
    f32x4 q0[D], q1[D];
#pragma unroll
    for (int i = 0; i < D; ++i) {
        asm volatile("global_load_dwordx4 %0, %1, off" : "=v"(q0[i]) : "v"(cptr(i, 0)));
        asm volatile("global_load_dwordx4 %0, %1, off" : "=v"(q1[i]) : "v"(cptr(i, 1)));
    }
#pragma unroll
    for (int kc = 0; kc < NKC; ++kc) {
        const int sl = kc % D;
        asm volatile("s_waitcnt vmcnt(%2)"
                     : "+v"(q0[sl]), "+v"(q1[sl])
                     : "i"((2 * ((NKC - kc) < D ? (NKC - kc) : D)) - 2));
        const bf16x8 fa0 = asbf(q0[sl]);
        const bf16x8 fa1 = asbf(q1[sl]);
        if (kc + D < NKC) {
            asm volatile("global_load_dwordx4 %0, %1, off" : "=v"(q0[sl]) : "v"(cptr(kc + D, 0)));
            asm volatile("global_load_dwordx4 %0, %1, off" : "=v"(q1[sl]) : "v"(cptr(kc + D, 1)));
        }
        const char* wrow = wres + (size_t)(((kc << 2) + akg) << 9);
        const bf16x8 fb0 = *(const bf16x8*)(wrow + (arow << 4));
        const bf16x8 fb1 = *(const bf16x8*)(wrow + ((16 + arow) << 4));
        acc[0][0] = __builtin_amdgcn_mfma_f32_16x16x32_bf16(fa0, fb0, acc[0][0], 0, 0, 0);
        acc[0][1] = __builtin_amdgcn_mfma_f32_16x16x32_bf16(fa0, fb1, acc[0][1], 0, 0, 0);
        acc[1][0] = __builtin_amdgcn_mfma_f32_16x16x32_bf16(fa1, fb0, acc[1][0], 0, 0, 0);
        acc[1][1] = __builtin_amdgcn_mfma_f32_16x16x32_bf16(fa1, fb1, acc[1][1], 0, 0, 0);
    }
    asm volatile("s_waitcnt vmcnt(0)");
}

// mask prefetch: 4 values per lane for this wave's (b,u) slice
__device__ __forceinline__ void pre_mask(const float* msk, int mrow, int u0, float o[4]) {
    const int lane = threadIdx.x & 63;
    const int u = u0 + (lane & 7);
#pragma unroll
    for (int r = 0; r < 4; ++r) {
        const int b = mrow + ((lane >> 3) << 2) + r;
        o[r] = msk[(size_t)b * HID + u];
    }
}

// Wave-private LSTM epilogue; c in regs; h2 written in chunk-fragment layout.
__device__ __forceinline__ void cell_epi_r(
    char* scrw, f32x4 acc[2][2], float creg[4],
    int mb, int np0, const float* bias_p,
    const float* mh4, const float* mc4, const float* ma4,
    short* h2_out, short* h2_aux)
{
    const int lane = threadIdx.x & 63;
#pragma unroll
    for (int mi = 0; mi < 2; ++mi)
#pragma unroll
        for (int ni = 0; ni < 2; ++ni) {
            const int row = mi * 16 + ((lane >> 4) << 2);
            const int col = ni * 16 + (lane & 15);
#pragma unroll
            for (int r = 0; r < 4; ++r)
                *(float*)(scrw + (row + r) * 128 + (col << 2)) = acc[mi][ni][r];
        }
    asm volatile("s_waitcnt lgkmcnt(0)" ::: "memory");
    const int ul = lane & 7;
    const int u0 = np0 >> 2;
    const int u = u0 + ul;
    const float4 bs = *(const float4*)(bias_p + np0 + (ul << 2));
    const int c_hi = u >> 5;
    const int gsub = (u >> 3) & 3;
#pragma unroll
    for (int r = 0; r < 4; ++r) {
        const int m = ((lane >> 3) << 2) + r;
        const int fh = m >> 4, r16 = m & 15;
        f32x4 gv = *(const f32x4*)(scrw + m * 128 + (ul << 4));
        const float gi = gv[0] + bs.x, gf = gv[1] + bs.y, gg = gv[2] + bs.z, go = gv[3] + bs.w;
        const float cn = sigf(gf) * creg[r] + sigf(gi) * tanhf(gg);
        const float h  = sigf(go) * tanhf(cn);
        creg[r] = mc4 ? cn * mc4[r] : cn;
        const float hm = mh4 ? h * mh4[r] : h;
        const size_t ci = ((size_t)((mb * 2 + fh) * 32 + c_hi) << 9) + ((r16 + (gsub << 4)) << 3) + ul;
        const short hh = f2bf(hm);
        h2_out[ci] = hh;
        h2_out[ci + 8192] = f2bf(hm - bf2f(hh));   // lo part: c+16 -> +16*512 shorts
        if (h2_aux) {
            const float ha = h * ma4[r];
            const short ah = f2bf(ha);
            h2_aux[ci] = ah;
            h2_aux[ci + 8192] = f2bf(ha - bf2f(ah));
        }
    }
}

// ---------------- persistent kernel (enc + dec) ----------------

__global__ void __launch_bounds__(512, 2) persist_kernel(
    const short* X2t,
    const short* __restrict__ W0, const short* __restrict__ W1,
    const short* __restrict__ Wd1, const short* __restrict__ Wd2,
    short* hA0, short* hA1, short* hB0, short* hB1, short* hd0, short* hd1,
    short* hBall0, short* hBallR,
    const float* __restrict__ bias0, const float* __restrict__ bias1,
    const float* __restrict__ biasd1, const float* __restrict__ biasd2,
    const float* __restrict__ enc_mask, const float* __restrict__ dec_h_mask,
    const float* __restrict__ dec_c_mask, unsigned* bar)
{
    extern __shared__ __align__(16) char lds[];
    const int bid = blockIdx.x;
    const int xcd = bid & 7;                       // XCD-clustered roles
    const int half = xcd >> 2;
    const int m0 = ((xcd >> 1) & 1) * 256;
    const int np0 = (((bid >> 3) << 1) | (xcd & 1)) * 32;
    const int u0 = np0 >> 2;
    const int w = threadIdx.x >> 6;
    const int mb = (m0 >> 5) + w;
    const int mrow = m0 + (w << 5);
    char* scrw = lds + 131072 + (w << 12);
    float creg[4] = {0.f, 0.f, 0.f, 0.f};

    auto hball = [&](int s) -> short* {
        return (s == 0) ? hBall0 : hBallR + (size_t)(s - 1) * 524288;
    };

    // ---- encoder ----
    load_wres(lds, (half ? W1 : W0) + (size_t)np0 * (half ? 2048 : 1280), half ? 2048 : 1280);
    __syncthreads();
    unsigned ep = 0;
    for (int tt = 0; tt <= TST; ++tt) {
        if (half == 0) {
            if (tt < TST) {
                const int t = tt;
                float ma[4];
                pre_mask(enc_mask + (size_t)t * SBZ, mrow, u0, ma);
                f32x4 acc[2][2];
#pragma unroll
                for (int a = 0; a < 2; ++a)
#pragma unroll
                    for (int b2 = 0; b2 < 2; ++b2) acc[a][b2] = (f32x4){0.f, 0.f, 0.f, 0.f};
                gemm_pipeC<8, 32>(lds, X2t + (size_t)t * 131072, (t & 1) ? hA1 : hA0, mb, acc);
                cell_epi_r(scrw, acc, creg, mb, np0, bias0, nullptr, nullptr, ma,
                           (t & 1) ? hA0 : hA1, (t & 1) ? hd1 : hd0);
            }
        } else {
            if (tt >= 1) {
                const int t = tt - 1;
                f32x4 acc[2][2];
#pragma unroll
                for (int a = 0; a < 2; ++a)
#pragma unroll
                    for (int b2 = 0; b2 < 2; ++b2) acc[a][b2] = (f32x4){0.f, 0.f, 0.f, 0.f};
                gemm_pipeC<32, 32>(lds, (t & 1) ? hd1 : hd0, (t & 1) ? hB1 : hB0, mb, acc);
                short* outp = (t == TST - 1) ? hball(0) : ((t & 1) ? hB0 : hB1);
                cell_epi_r(scrw, acc, creg, mb, np0, bias1, nullptr, nullptr, nullptr,
                           outp, nullptr);
            }
        }
        gbar2(bar, bid, ++ep);
    }

    // ---- decoder ----
    load_wres(lds, (half ? Wd2 : Wd1) + (size_t)np0 * 2048, 2048);
    __syncthreads();
    for (int s = 0; s < HOR - 1; ++s) {
        if (half == 0) {
            float mh[4], mc[4];
            pre_mask(dec_h_mask + (size_t)s * SBZ, mrow, u0, mh);
            pre_mask(dec_c_mask + (size_t)s * SBZ, mrow, u0, mc);
            f32x4 acc[2][2];
#pragma unroll
            for (int a = 0; a < 2; ++a)
#pragma unroll
                for (int b2 = 0; b2 < 2; ++b2) acc[a][b2] = (f32x4){0.f, 0.f, 0.f, 0.f};
            gemm_pipeC<32, 32>(lds, hball(s), (s & 1) ? hA1 : hA0, mb, acc);
            cell_epi_r(scrw, acc, creg, mb, np0, biasd1, mh, mc, nullptr,
                       (s & 1) ? hA0 : hA1, nullptr);
        }
        gbar2(bar, bid, ++ep);
        if (half == 1) {
            f32x4 acc[2][2];
#pragma unroll
            for (int a = 0; a < 2; ++a)
#pragma unroll
                for (int b2 = 0; b2 < 2; ++b2) acc[a][b2] = (f32x4){0.f, 0.f, 0.f, 0.f};
            gemm_pipeC<32, 32>(lds, (s & 1) ? hA0 : hA1, hball(s), mb, acc);
            cell_epi_r(scrw, acc, creg, mb, np0, biasd2, nullptr, nullptr, nullptr,
                       hball(s + 1), nullptr);
        }
        gbar2(bar, bid, ++ep);
    }
}

// ---------------- batched projection: pred_all[s][b*128+n] = hBall[s] @ Wp^T + bp ----------------

__global__ void __launch_bounds__(512, 2) proj_kernel(
    const short* hBall0, const short* hBallR, const short* __restrict__ W2p,
    const float* __restrict__ bp, float* __restrict__ pred_all)
{
    extern __shared__ __align__(16) char lds[];
    const int bid = blockIdx.x;                 // 256 = 32 s * 2 bh * 4 n0
    const int s = bid >> 3, q = bid & 7;
    const int bh = q >> 2, n0p = (q & 3) * 32;
    load_wres(lds, W2p + (size_t)n0p * 1024, 1024);   // 64 KB resident
    const int w = threadIdx.x >> 6, lane = threadIdx.x & 63;
    char* scrw = lds + 65536 + w * 4608;
    const int mb = bh * 8 + w;
    const short* A = (s == 0) ? hBall0 : hBallR + (size_t)(s - 1) * 524288;
    __syncthreads();
    f32x4 acc[2][2];
#pragma unroll
    for (int a = 0; a < 2; ++a)
#pragma unroll
        for (int b2 = 0; b2 < 2; ++b2) acc[a][b2] = (f32x4){0.f, 0.f, 0.f, 0.f};
    gemm_pipeC<32, 0>(lds, A, A, mb, acc);
    // stage to LDS (stride 144B) then coalesced-ish writes
#pragma unroll
    for (int mi = 0; mi < 2; ++mi)
#pragma unroll
        for (int ni = 0; ni < 2; ++ni) {
            const int row = mi * 16 + ((lane >> 4) << 2);
            const int col = ni * 16 + (lane & 15);
#pragma unroll
            for (int r = 0; r < 4; ++r)
                *(float*)(scrw + (row + r) * 144 + (col << 2)) = acc[mi][ni][r];
        }
    asm volatile("s_waitcnt lgkmcnt(0)" ::: "memory");
    const int rr = lane >> 1, hf = lane & 1;
    float* dst = pred_all + (size_t)s * (BAT * NIN)
               + (size_t)(bh * 256 + w * 32 + rr) * NIN + n0p + hf * 16;
#pragma unroll
    for (int t4 = 0; t4 < 4; ++t4) {
        f32x4 v = *(const f32x4*)(scrw + rr * 144 + hf * 64 + t4 * 16);
        const float4 b4 = *(const float4*)(bp + n0p + hf * 16 + t4 * 4);
        v[0] += b4.x; v[1] += b4.y; v[2] += b4.z; v[3] += b4.w;
        *(f32x4*)(dst + t4 * 4) = v;
    }
}

// out[(b*128+n)*32 + s] = pred_all[s][b*128+n]
__global__ __launch_bounds__(256) void transpose_out(const float* __restrict__ pred_all,
                                                     float* __restrict__ out) {
    __shared__ float tl[32][65];
    const int base = blockIdx.x * 64;
    const int tid = threadIdx.x;
    for (int i = tid; i < 32 * 64; i += 256) {
        int s = i >> 6, f = i & 63;
        tl[s][f] = pred_all[(size_t)s * (BAT * NIN) + base + f];
    }
    __syncthreads();
    for (int i = tid; i < 64 * 32; i += 256) {
        int f = i >> 5, s = i & 31;
        out[(size_t)(base + f) * HOR + s] = tl[s][f];
    }
}

// ---------------- host ----------------

extern "C" void kernel_launch(void* const* d_in, const int* in_sizes, int n_in,
                              void* d_out, int out_size, void* d_ws, size_t ws_size,
                              hipStream_t stream) {
    (void)in_sizes; (void)n_in; (void)out_size; (void)ws_size;
    const float* window = (const float*)d_in[0];
    const float* Wih0 = (const float*)d_in[1];
    const float* Whh0 = (const float*)d_in[2];
    const float* bih0 = (const float*)d_in[3];
    const float* bhh0 = (const float*)d_in[4];
    const float* Wih1 = (const float*)d_in[5];
    const float* Whh1 = (const float*)d_in[6];
    const float* bih1 = (const float*)d_in[7];
    const float* bhh1 = (const float*)d_in[8];
    const float* Wc1i = (const float*)d_in[9];
    const float* Wc1h = (const float*)d_in[10];
    const float* bc1i = (const float*)d_in[11];
    const float* bc1h = (const float*)d_in[12];
    const float* Wc2i = (const float*)d_in[13];
    const float* Wc2h = (const float*)d_in[14];
    const float* bc2i = (const float*)d_in[15];
    const float* bc2h = (const float*)d_in[16];
    const float* Wp   = (const float*)d_in[17];
    const float* bp   = (const float*)d_in[18];
    const float* enc_mask   = (const float*)d_in[19];
    const float* dec_h_mask = (const float*)d_in[20];
    const float* dec_c_mask = (const float*)d_in[21];
    float* out = (float*)d_out;

    char* base = (char*)d_ws;
    size_t off = 0;
    auto take = [&](size_t bytes) -> char* {
        off = (off + 255) & ~(size_t)255;
        char* r = base + off; off += bytes; return r;
    };
    short* W2e0 = (short*)take((size_t)2048 * 1280 * 2);
    short* W2e1 = (short*)take((size_t)2048 * 2048 * 2);
    short* W2d1 = (short*)take((size_t)2048 * 2048 * 2);   // fused [Wfuse|Wc1h]
    short* W2d2 = (short*)take((size_t)2048 * 2048 * 2);
    short* W2p  = (short*)take((size_t)128 * 1024 * 2);
    float* Wfuse = (float*)take((size_t)2048 * 512 * 4);
    float* badd  = (float*)take((size_t)2048 * 4);
    float* bias0 = (float*)take((size_t)2048 * 4);
    float* bias1 = (float*)take((size_t)2048 * 4);
    float* biasd1 = (float*)take((size_t)2048 * 4);
    float* biasd2 = (float*)take((size_t)2048 * 4);
    short* hA0 = (short*)take((size_t)524288 * 2);
    short* hA1 = (short*)take((size_t)524288 * 2);
    short* hB0 = (short*)take((size_t)524288 * 2);
    short* hB1 = (short*)take((size_t)524288 * 2);
    short* hd0 = (short*)take((size_t)524288 * 2);
    short* hd1 = (short*)take((size_t)524288 * 2);
    short* hBall0 = (short*)take((size_t)524288 * 2);
    float* pred_all = (float*)take((size_t)HOR * BAT * NIN * 4);
    unsigned* bars = (unsigned*)take(16384);
    short* X2t = (short*)take((size_t)TST * 131072 * 2);
    short* hBallR = X2t;   // decoder h-history overlaps dead X2 region (31 MB <= 32 MB)

    // prep (re-done every call; deterministic)
    prep_fuse<<<(2048 * 512 + 255) / 256, 256, 0, stream>>>(Wc1i, Wp, Wfuse);
    prep_badd<<<8, 256, 0, stream>>>(Wc1i, bp, badd);
    prep_wp<<<(128 * 1024 + 255) / 256, 256, 0, stream>>>(Wp, W2p);
    prep_w<<<(2048 * 1280 + 255) / 256, 256, 0, stream>>>(Wih0, Whh0, W2e0, NIN, 1280);
    prep_w<<<(2048 * 2048 + 255) / 256, 256, 0, stream>>>(Wih1, Whh1, W2e1, HID, 2048);
    prep_w<<<(2048 * 2048 + 255) / 256, 256, 0, stream>>>(Wfuse, Wc1h, W2d1, HID, 2048);
    prep_w<<<(2048 * 2048 + 255) / 256, 256, 0, stream>>>(Wc2i, Wc2h, W2d2, HID, 2048);
    prep_bias<<<8, 256, 0, stream>>>(bih0, bhh0, nullptr, bias0);
    prep_bias<<<8, 256, 0, stream>>>(bih1, bhh1, nullptr, bias1);
    prep_bias<<<8, 256, 0, stream>>>(bc1i, bc1h, badd, biasd1);
    prep_bias<<<8, 256, 0, stream>>>(bc2i, bc2h, nullptr, biasd2);
    prep_x<<<(int)(((size_t)TST * BAT * NIN + 255) / 256), 256, 0, stream>>>(window, X2t);
    hipMemsetAsync(hA0, 0, (size_t)524288 * 2, stream);
    hipMemsetAsync(hB0, 0, (size_t)524288 * 2, stream);
    hipMemsetAsync(bars, 0, 16384, stream);

    hipFuncSetAttribute((const void*)persist_kernel, hipFuncAttributeMaxDynamicSharedMemorySize, 163840);
    hipFuncSetAttribute((const void*)proj_kernel, hipFuncAttributeMaxDynamicSharedMemorySize, 163840);

    persist_kernel<<<256, 512, 163840, stream>>>(
        X2t, W2e0, W2e1, W2d1, W2d2,
        hA0, hA1, hB0, hB1, hd0, hd1,
        hBall0, hBallR,
        bias0, bias1, biasd1, biasd2,
        enc_mask, dec_h_mask, dec_c_mask, bars);

    proj_kernel<<<256, 512, 102400, stream>>>(hBall0, hBallR, W2p, bp, pred_all);

    transpose_out<<<(BAT * NIN) / 64, 256, 0, stream>>>(pred_all, out);
}

// Round 10
// 2753.601 us; speedup vs baseline: 6.9557x; 1.5481x over previous
//
#include <hip/hip_runtime.h>
#include <math.h>

#define HID 512
#define BAT 512
#define NIN 128
#define TST 128
#define HOR 32
#define SBZ ((size_t)BAT * HID)

using bf16x8 = __attribute__((ext_vector_type(8))) __bf16;
using f32x4  = __attribute__((ext_vector_type(4))) float;

__device__ __forceinline__ float sigf(float x) { return 1.0f / (1.0f + __expf(-x)); }
__device__ __forceinline__ float tanhfast(float x) { return 1.0f - 2.0f / (__expf(2.0f * x) + 1.0f); }

__device__ __forceinline__ short f2bf(float x) {
    union { float f; unsigned u; } v; v.f = x;
    unsigned r = (v.u + 0x7FFFu + ((v.u >> 16) & 1u)) >> 16;
    return (short)r;
}
__device__ __forceinline__ float bf2f(short s) {
    union { unsigned u; float f; } v; v.u = ((unsigned)(unsigned short)s) << 16;
    return v.f;
}
__device__ __forceinline__ bf16x8 asbf(f32x4 v) {
    union { f32x4 f; bf16x8 b; } u; u.f = v; return u.b;
}

// Fence-free hierarchical grid barrier. All cross-block DATA goes through sc0sc1
// (L3-coherent) loads/stores, so no wbl2/inv is needed; counters are relaxed
// agent atomics (sc1 -> coherence point). __syncthreads drains vmcnt per wave
// before the arrive-add, giving store->add ordering.
__device__ __forceinline__ void gbar3(unsigned* bar, int bid, unsigned ep) {
    __syncthreads();
    if (threadIdx.x == 0) {
        unsigned* leaf = bar + ((unsigned)bid >> 3) * 32;
        unsigned* root = bar + 1024;
        unsigned* flag = bar + 1056;
        unsigned old = __hip_atomic_fetch_add(leaf, 1u, __ATOMIC_RELAXED, __HIP_MEMORY_SCOPE_AGENT);
        if (old == 8u * ep - 1u) {
            unsigned ro = __hip_atomic_fetch_add(root, 1u, __ATOMIC_RELAXED, __HIP_MEMORY_SCOPE_AGENT);
            if (ro == 32u * ep - 1u)
                __hip_atomic_store(flag, ep, __ATOMIC_RELAXED, __HIP_MEMORY_SCOPE_AGENT);
        }
        int spin = 0;
        while (__hip_atomic_load(flag, __ATOMIC_RELAXED, __HIP_MEMORY_SCOPE_AGENT) < ep) {
            __builtin_amdgcn_s_sleep(1);
            if (((++spin) & 63) == 0)
                __hip_atomic_fetch_add(flag, 0u, __ATOMIC_RELAXED, __HIP_MEMORY_SCOPE_AGENT);
        }
    }
    __syncthreads();
}

// ---------------- prep kernels ----------------

// permuted weight rows: n' = u*4 + gate; cols [Wih_hi|Wih_lo|Whh_hi|Whh_lo]; row-major [2048][Kp]
__global__ __launch_bounds__(256) void prep_w(const float* __restrict__ Wih,
                                              const float* __restrict__ Whh,
                                              short* __restrict__ W2, int Kx, int Kp) {
    size_t i = (size_t)blockIdx.x * 256 + threadIdx.x;
    if (i >= (size_t)2048 * Kp) return;
    int np = (int)(i / Kp), kp = (int)(i % Kp);
    int u = np >> 2, gate = np & 3;
    int on = gate * HID + u;
    float w; bool islo = false;
    if (kp < Kx)                { w = Wih[(size_t)on * Kx + kp]; }
    else if (kp < 2 * Kx)       { w = Wih[(size_t)on * Kx + (kp - Kx)]; islo = true; }
    else if (kp < 2 * Kx + HID) { w = Whh[(size_t)on * HID + (kp - 2 * Kx)]; }
    else                        { w = Whh[(size_t)on * HID + (kp - 2 * Kx - HID)]; islo = true; }
    short hi = f2bf(w);
    W2[i] = islo ? f2bf(w - bf2f(hi)) : hi;
}

// X2t: per-t chunk layout, chunk(mb2, c) of 512 shorts, lane-fragment order.
__global__ __launch_bounds__(256) void prep_x(const float* __restrict__ window,
                                              short* __restrict__ X2t) {
    size_t i = (size_t)blockIdx.x * 256 + threadIdx.x;
    if (i >= (size_t)TST * BAT * NIN) return;
    int n = (int)(i & 127);
    int b = (int)((i >> 7) & 511);
    int t = (int)(i >> 16);
    float x = window[(size_t)b * (TST * NIN) + (size_t)t * NIN + n];
    short hi = f2bf(x);
    short lo = f2bf(x - bf2f(hi));
    int mb2 = ((b >> 5) << 1) | ((b >> 4) & 1);
    int l = (b & 15) + (((n >> 3) & 3) << 4);
    int e = n & 7;
    size_t base = (size_t)t * 131072 + ((size_t)(mb2 * 8 + (n >> 5)) << 9) + l * 8 + e;
    X2t[base] = hi;
    X2t[base + 2048] = lo;
}

__global__ __launch_bounds__(256) void prep_fuse(const float* __restrict__ Wc1i,
                                                 const float* __restrict__ Wp,
                                                 float* __restrict__ Wfuse) {
    size_t i = (size_t)blockIdx.x * 256 + threadIdx.x;
    if (i >= (size_t)2048 * 512) return;
    int on = (int)(i >> 9), k = (int)(i & 511);
    float s = 0.f;
    for (int n = 0; n < NIN; ++n) s += Wc1i[(size_t)on * NIN + n] * Wp[(size_t)n * HID + k];
    Wfuse[i] = s;
}

__global__ __launch_bounds__(256) void prep_badd(const float* __restrict__ Wc1i,
                                                 const float* __restrict__ bp,
                                                 float* __restrict__ badd) {
    int on = blockIdx.x * 256 + threadIdx.x;
    if (on >= 2048) return;
    float s = 0.f;
    for (int n = 0; n < NIN; ++n) s += Wc1i[(size_t)on * NIN + n] * bp[n];
    badd[on] = s;
}

__global__ __launch_bounds__(256) void prep_bias(const float* __restrict__ bih,
                                                 const float* __restrict__ bhh,
                                                 const float* __restrict__ badd,
                                                 float* __restrict__ bout) {
    int np = blockIdx.x * 256 + threadIdx.x;
    if (np >= 2048) return;
    int on = (np & 3) * HID + (np >> 2);
    float v = bih[on] + bhh[on];
    if (badd) v += badd[on];
    bout[np] = v;
}

// W2p row-major [128][1024]: [0,512)=Wp_hi, [512,1024)=Wp_lo
__global__ __launch_bounds__(256) void prep_wp(const float* __restrict__ Wp,
                                               short* __restrict__ W2p) {
    int i = blockIdx.x * 256 + threadIdx.x;
    if (i >= 128 * 1024) return;
    int n = i >> 10, k = i & 1023;
    float w = Wp[(size_t)n * HID + (k & 511)];
    short hi = f2bf(w);
    W2p[i] = (k < 512) ? hi : f2bf(w - bf2f(hi));
}

// ---------------- device building blocks ----------------

// resident W: 32 rows x K, k-major granules: lds[j*512 + r*16]
__device__ __forceinline__ void load_wres(char* lds, const short* Wg, int K) {
    const int tid = threadIdx.x;
    const int r = tid >> 4;
    const int cnt = K >> 7;
    const int jb = (tid & 15) * cnt;
    for (int q = 0; q < cnt; ++q) {
        int j = jb + q;
        bf16x8 v = *(const bf16x8*)(Wg + (size_t)r * K + j * 8);
        *(bf16x8*)(lds + j * 512 + r * 16) = v;
    }
}

// mask prefetch via volatile-asm loads issued BEFORE the gemm prologue, so they
// are strictly OLDER than the counted loads (vmcnt arithmetic stays exact).
__device__ __forceinline__ void pre_mask_asm(const float* msk, int mrow, int u0, float o[4]) {
    const int lane = threadIdx.x & 63;
    const float* p = msk + (size_t)(mrow + ((lane >> 3) << 2)) * HID + u0 + (lane & 7);
#pragma unroll
    for (int r = 0; r < 4; ++r)
        asm volatile("global_load_dword %0, %1, off" : "=v"(o[r]) : "v"(p + (size_t)r * HID));
}

// Wave-private GEMM 32(m) x 32(n') over chunked A (contiguous 1KB per load, sc0sc1
// L3-coherent), counted-vmcnt pipeline depth D=16; W from resident LDS.
template<int C0, int C1>
__device__ __forceinline__ void gemm_pipeC(
    const char* wres, const short* a0t, const short* a1t,
    int mb, f32x4 acc[2][2])
{
    constexpr int NKC = C0 + C1;
    constexpr int D = 16;
    const int lane = threadIdx.x & 63;
    const int arow = lane & 15, akg = lane >> 4;
    const size_t lb = (size_t)lane << 4;
    const char* base0 = (const char*)a0t;
    const char* base1 = (const char*)a1t;
    auto cptr = [&](int kc, int fh) -> const char* {
        return (kc < C0)
            ? base0 + (((size_t)(mb * 2 + fh) * C0 + kc) << 10) + lb
            : base1 + (((size_t)(mb * 2 + fh) * C1 + (kc - C0)) << 10) + lb;
    };
    f32x4 q0[D], q1[D];
#pragma unroll
    for (int i = 0; i < D; ++i) {
        asm volatile("global_load_dwordx4 %0, %1, off sc0 sc1" : "=v"(q0[i]) : "v"(cptr(i, 0)));
        asm volatile("global_load_dwordx4 %0, %1, off sc0 sc1" : "=v"(q1[i]) : "v"(cptr(i, 1)));
    }
#pragma unroll
    for (int kc = 0; kc < NKC; ++kc) {
        const int sl = kc % D;
        asm volatile("s_waitcnt vmcnt(%2)"
                     : "+v"(q0[sl]), "+v"(q1[sl])
                     : "i"((2 * ((NKC - kc) < D ? (NKC - kc) : D)) - 2));
        const bf16x8 fa0 = asbf(q0[sl]);
        const bf16x8 fa1 = asbf(q1[sl]);
        if (kc + D < NKC) {
            asm volatile("global_load_dwordx4 %0, %1, off sc0 sc1" : "=v"(q0[sl]) : "v"(cptr(kc + D, 0)));
            asm volatile("global_load_dwordx4 %0, %1, off sc0 sc1" : "=v"(q1[sl]) : "v"(cptr(kc + D, 1)));
        }
        const char* wrow = wres + (size_t)(((kc << 2) + akg) << 9);
        const bf16x8 fb0 = *(const bf16x8*)(wrow + (arow << 4));
        const bf16x8 fb1 = *(const bf16x8*)(wrow + ((16 + arow) << 4));
        acc[0][0] = __builtin_amdgcn_mfma_f32_16x16x32_bf16(fa0, fb0, acc[0][0], 0, 0, 0);
        acc[0][1] = __builtin_amdgcn_mfma_f32_16x16x32_bf16(fa0, fb1, acc[0][1], 0, 0, 0);
        acc[1][0] = __builtin_amdgcn_mfma_f32_16x16x32_bf16(fa1, fb0, acc[1][0], 0, 0, 0);
        acc[1][1] = __builtin_amdgcn_mfma_f32_16x16x32_bf16(fa1, fb1, acc[1][1], 0, 0, 0);
    }
    asm volatile("s_waitcnt vmcnt(0)");
}

// Wave-private LSTM epilogue; c in regs; h2 staged via LDS then written as
// coalesced 256B sc0sc1 dword stores (4 main + 4 aux segments per wave).
__device__ __forceinline__ void cell_epi_r(
    char* scrw, f32x4 acc[2][2], float creg[4],
    int mb, int np0, const float* bias_p,
    const float* mh4, const float* mc4, const float* ma4,
    short* h2_out, short* h2_aux)
{
    const int lane = threadIdx.x & 63;
    // 1) gates -> LDS
#pragma unroll
    for (int mi = 0; mi < 2; ++mi)
#pragma unroll
        for (int ni = 0; ni < 2; ++ni) {
            const int row = mi * 16 + ((lane >> 4) << 2);
            const int col = ni * 16 + (lane & 15);
#pragma unroll
            for (int r = 0; r < 4; ++r)
                *(float*)(scrw + (row + r) * 128 + (col << 2)) = acc[mi][ni][r];
        }
    asm volatile("s_waitcnt lgkmcnt(0)" ::: "memory");
    // 2) read own gate quads
    const int ul = lane & 7, g = lane >> 3;
    f32x4 gv[4];
#pragma unroll
    for (int r = 0; r < 4; ++r)
        gv[r] = *(const f32x4*)(scrw + ((g << 2) + r) * 128 + (ul << 4));
    asm volatile("s_waitcnt lgkmcnt(0)" ::: "memory");
    // 3) pointwise + stage bf16 pairs into scrw[0..2KB)
    const float4 bs = *(const float4*)(bias_p + np0 + (ul << 2));
#pragma unroll
    for (int r = 0; r < 4; ++r) {
        const int m = (g << 2) + r;
        const int fh = m >> 4, r16 = m & 15;
        const float gi = gv[r][0] + bs.x, gf = gv[r][1] + bs.y;
        const float gg = gv[r][2] + bs.z, go = gv[r][3] + bs.w;
        const float cn = sigf(gf) * creg[r] + sigf(gi) * tanhfast(gg);
        const float h  = sigf(go) * tanhfast(cn);
        creg[r] = mc4 ? cn * mc4[r] : cn;
        const float hm = mh4 ? h * mh4[r] : h;
        const short hh = f2bf(hm);
        const int idx2 = (r16 << 3) + ul;
        *(short*)(scrw + (fh * 2 + 0) * 256 + idx2 * 2) = hh;
        *(short*)(scrw + (fh * 2 + 1) * 256 + idx2 * 2) = f2bf(hm - bf2f(hh));
        if (h2_aux) {
            const float ha = h * ma4[r];
            const short ah = f2bf(ha);
            *(short*)(scrw + 1024 + (fh * 2 + 0) * 256 + idx2 * 2) = ah;
            *(short*)(scrw + 1024 + (fh * 2 + 1) * 256 + idx2 * 2) = f2bf(ha - bf2f(ah));
        }
    }
    // 4) coalesced sc1 stores
    const int u0l = np0 >> 2;
    const int c_hi = u0l >> 5, gsub = (u0l >> 3) & 3;
    unsigned vmain[4], vaux[4];
#pragma unroll
    for (int s = 0; s < 4; ++s)
        vmain[s] = *(const unsigned*)(scrw + s * 256 + (lane << 2));
    if (h2_aux)
#pragma unroll
        for (int s = 0; s < 4; ++s)
            vaux[s] = *(const unsigned*)(scrw + 1024 + s * 256 + (lane << 2));
    asm volatile("s_waitcnt lgkmcnt(0)" ::: "memory");
#pragma unroll
    for (int s = 0; s < 4; ++s) {
        const int fh = s >> 1, part = s & 1;
        const unsigned* dst = (const unsigned*)(h2_out
            + ((size_t)((mb * 2 + fh) * 32 + c_hi) << 9) + part * 8192 + (gsub << 7)) + lane;
        asm volatile("global_store_dword %0, %1, off sc0 sc1" :: "v"(dst), "v"(vmain[s]));
    }
    if (h2_aux)
#pragma unroll
        for (int s = 0; s < 4; ++s) {
            const int fh = s >> 1, part = s & 1;
            const unsigned* dst = (const unsigned*)(h2_aux
                + ((size_t)((mb * 2 + fh) * 32 + c_hi) << 9) + part * 8192 + (gsub << 7)) + lane;
            asm volatile("global_store_dword %0, %1, off sc0 sc1" :: "v"(dst), "v"(vaux[s]));
        }
}

// ---------------- persistent kernel (enc + dec) ----------------

__global__ void __launch_bounds__(512, 2) persist_kernel(
    const short* X2t,
    const short* __restrict__ W0, const short* __restrict__ W1,
    const short* __restrict__ Wd1, const short* __restrict__ Wd2,
    short* hA0, short* hA1, short* hB0, short* hB1, short* hd0, short* hd1,
    short* hBall0, short* hBallR,
    const float* __restrict__ bias0, const float* __restrict__ bias1,
    const float* __restrict__ biasd1, const float* __restrict__ biasd2,
    const float* __restrict__ enc_mask, const float* __restrict__ dec_h_mask,
    const float* __restrict__ dec_c_mask, unsigned* bar)
{
    extern __shared__ __align__(16) char lds[];
    const int bid = blockIdx.x;
    const int xcd = bid & 7;                       // XCD-clustered roles
    const int half = xcd >> 2;
    const int m0 = ((xcd >> 1) & 1) * 256;
    const int np0 = (((bid >> 3) << 1) | (xcd & 1)) * 32;
    const int u0 = np0 >> 2;
    const int w = threadIdx.x >> 6;
    const int mb = (m0 >> 5) + w;
    const int mrow = m0 + (w << 5);
    char* scrw = lds + 131072 + (w << 12);
    float creg[4] = {0.f, 0.f, 0.f, 0.f};

    auto hball = [&](int s) -> short* {
        return (s == 0) ? hBall0 : hBallR + (size_t)(s - 1) * 524288;
    };

    // ---- encoder ----
    load_wres(lds, (half ? W1 : W0) + (size_t)np0 * (half ? 2048 : 1280), half ? 2048 : 1280);
    __syncthreads();
    unsigned ep = 0;
    for (int tt = 0; tt <= TST; ++tt) {
        if (half == 0) {
            if (tt < TST) {
                const int t = tt;
                float ma[4];
                pre_mask_asm(enc_mask + (size_t)t * SBZ, mrow, u0, ma);
                f32x4 acc[2][2];
#pragma unroll
                for (int a = 0; a < 2; ++a)
#pragma unroll
                    for (int b2 = 0; b2 < 2; ++b2) acc[a][b2] = (f32x4){0.f, 0.f, 0.f, 0.f};
                gemm_pipeC<8, 32>(lds, X2t + (size_t)t * 131072, (t & 1) ? hA1 : hA0, mb, acc);
                cell_epi_r(scrw, acc, creg, mb, np0, bias0, nullptr, nullptr, ma,
                           (t & 1) ? hA0 : hA1, (t & 1) ? hd1 : hd0);
            }
        } else {
            if (tt >= 1) {
                const int t = tt - 1;
                f32x4 acc[2][2];
#pragma unroll
                for (int a = 0; a < 2; ++a)
#pragma unroll
                    for (int b2 = 0; b2 < 2; ++b2) acc[a][b2] = (f32x4){0.f, 0.f, 0.f, 0.f};
                gemm_pipeC<32, 32>(lds, (t & 1) ? hd1 : hd0, (t & 1) ? hB1 : hB0, mb, acc);
                short* outp = (t == TST - 1) ? hball(0) : ((t & 1) ? hB0 : hB1);
                cell_epi_r(scrw, acc, creg, mb, np0, bias1, nullptr, nullptr, nullptr,
                           outp, nullptr);
            }
        }
        gbar3(bar, bid, ++ep);
    }

    // ---- decoder ----
    load_wres(lds, (half ? Wd2 : Wd1) + (size_t)np0 * 2048, 2048);
    __syncthreads();
    for (int s = 0; s < HOR - 1; ++s) {
        if (half == 0) {
            float mh[4], mc[4];
            pre_mask_asm(dec_h_mask + (size_t)s * SBZ, mrow, u0, mh);
            pre_mask_asm(dec_c_mask + (size_t)s * SBZ, mrow, u0, mc);
            f32x4 acc[2][2];
#pragma unroll
            for (int a = 0; a < 2; ++a)
#pragma unroll
                for (int b2 = 0; b2 < 2; ++b2) acc[a][b2] = (f32x4){0.f, 0.f, 0.f, 0.f};
            gemm_pipeC<32, 32>(lds, hball(s), (s & 1) ? hA1 : hA0, mb, acc);
            cell_epi_r(scrw, acc, creg, mb, np0, biasd1, mh, mc, nullptr,
                       (s & 1) ? hA0 : hA1, nullptr);
        }
        gbar3(bar, bid, ++ep);
        if (half == 1) {
            f32x4 acc[2][2];
#pragma unroll
            for (int a = 0; a < 2; ++a)
#pragma unroll
                for (int b2 = 0; b2 < 2; ++b2) acc[a][b2] = (f32x4){0.f, 0.f, 0.f, 0.f};
            gemm_pipeC<32, 32>(lds, (s & 1) ? hA0 : hA1, hball(s), mb, acc);
            cell_epi_r(scrw, acc, creg, mb, np0, biasd2, nullptr, nullptr, nullptr,
                       hball(s + 1), nullptr);
        }
        gbar3(bar, bid, ++ep);
    }
}

// ---------------- batched projection: pred_all[s][b*128+n] = hBall[s] @ Wp^T + bp ----------------

__global__ void __launch_bounds__(512, 2) proj_kernel(
    const short* hBall0, const short* hBallR, const short* __restrict__ W2p,
    const float* __restrict__ bp, float* __restrict__ pred_all)
{
    extern __shared__ __align__(16) char lds[];
    const int bid = blockIdx.x;                 // 256 = 32 s * 2 bh * 4 n0
    const int s = bid >> 3, q = bid & 7;
    const int bh = q >> 2, n0p = (q & 3) * 32;
    load_wres(lds, W2p + (size_t)n0p * 1024, 1024);   // 64 KB resident
    const int w = threadIdx.x >> 6, lane = threadIdx.x & 63;
    char* scrw = lds + 65536 + w * 4608;
    const int mb = bh * 8 + w;
    const short* A = (s == 0) ? hBall0 : hBallR + (size_t)(s - 1) * 524288;
    __syncthreads();
    f32x4 acc[2][2];
#pragma unroll
    for (int a = 0; a < 2; ++a)
#pragma unroll
        for (int b2 = 0; b2 < 2; ++b2) acc[a][b2] = (f32x4){0.f, 0.f, 0.f, 0.f};
    gemm_pipeC<32, 0>(lds, A, A, mb, acc);
#pragma unroll
    for (int mi = 0; mi < 2; ++mi)
#pragma unroll
        for (int ni = 0; ni < 2; ++ni) {
            const int row = mi * 16 + ((lane >> 4) << 2);
            const int col = ni * 16 + (lane & 15);
#pragma unroll
            for (int r = 0; r < 4; ++r)
                *(float*)(scrw + (row + r) * 144 + (col << 2)) = acc[mi][ni][r];
        }
    asm volatile("s_waitcnt lgkmcnt(0)" ::: "memory");
    const int rr = lane >> 1, hf = lane & 1;
    float* dst = pred_all + (size_t)s * (BAT * NIN)
               + (size_t)(bh * 256 + w * 32 + rr) * NIN + n0p + hf * 16;
#pragma unroll
    for (int t4 = 0; t4 < 4; ++t4) {
        f32x4 v = *(const f32x4*)(scrw + rr * 144 + hf * 64 + t4 * 16);
        const float4 b4 = *(const float4*)(bp + n0p + hf * 16 + t4 * 4);
        v[0] += b4.x; v[1] += b4.y; v[2] += b4.z; v[3] += b4.w;
        *(f32x4*)(dst + t4 * 4) = v;
    }
}

// out[(b*128+n)*32 + s] = pred_all[s][b*128+n]
__global__ __launch_bounds__(256) void transpose_out(const float* __restrict__ pred_all,
                                                     float* __restrict__ out) {
    __shared__ float tl[32][65];
    const int base = blockIdx.x * 64;
    const int tid = threadIdx.x;
    for (int i = tid; i < 32 * 64; i += 256) {
        int s = i >> 6, f = i & 63;
        tl[s][f] = pred_all[(size_t)s * (BAT * NIN) + base + f];
    }
    __syncthreads();
    for (int i = tid; i < 64 * 32; i += 256) {
        int f = i >> 5, s = i & 31;
        out[(size_t)(base + f) * HOR + s] = tl[s][f];
    }
}

// ---------------- host ----------------

extern "C" void kernel_launch(void* const* d_in, const int* in_sizes, int n_in,
                              void* d_out, int out_size, void* d_ws, size_t ws_size,
                              hipStream_t stream) {
    (void)in_sizes; (void)n_in; (void)out_size; (void)ws_size;
    const float* window = (const float*)d_in[0];
    const float* Wih0 = (const float*)d_in[1];
    const float* Whh0 = (const float*)d_in[2];
    const float* bih0 = (const float*)d_in[3];
    const float* bhh0 = (const float*)d_in[4];
    const float* Wih1 = (const float*)d_in[5];
    const float* Whh1 = (const float*)d_in[6];
    const float* bih1 = (const float*)d_in[7];
    const float* bhh1 = (const float*)d_in[8];
    const float* Wc1i = (const float*)d_in[9];
    const float* Wc1h = (const float*)d_in[10];
    const float* bc1i = (const float*)d_in[11];
    const float* bc1h = (const float*)d_in[12];
    const float* Wc2i = (const float*)d_in[13];
    const float* Wc2h = (const float*)d_in[14];
    const float* bc2i = (const float*)d_in[15];
    const float* bc2h = (const float*)d_in[16];
    const float* Wp   = (const float*)d_in[17];
    const float* bp   = (const float*)d_in[18];
    const float* enc_mask   = (const float*)d_in[19];
    const float* dec_h_mask = (const float*)d_in[20];
    const float* dec_c_mask = (const float*)d_in[21];
    float* out = (float*)d_out;

    char* base = (char*)d_ws;
    size_t off = 0;
    auto take = [&](size_t bytes) -> char* {
        off = (off + 255) & ~(size_t)255;
        char* r = base + off; off += bytes; return r;
    };
    short* W2e0 = (short*)take((size_t)2048 * 1280 * 2);
    short* W2e1 = (short*)take((size_t)2048 * 2048 * 2);
    short* W2d1 = (short*)take((size_t)2048 * 2048 * 2);   // fused [Wfuse|Wc1h]
    short* W2d2 = (short*)take((size_t)2048 * 2048 * 2);
    short* W2p  = (short*)take((size_t)128 * 1024 * 2);
    float* Wfuse = (float*)take((size_t)2048 * 512 * 4);
    float* badd  = (float*)take((size_t)2048 * 4);
    float* bias0 = (float*)take((size_t)2048 * 4);
    float* bias1 = (float*)take((size_t)2048 * 4);
    float* biasd1 = (float*)take((size_t)2048 * 4);
    float* biasd2 = (float*)take((size_t)2048 * 4);
    short* hA0 = (short*)take((size_t)524288 * 2);
    short* hA1 = (short*)take((size_t)524288 * 2);
    short* hB0 = (short*)take((size_t)524288 * 2);
    short* hB1 = (short*)take((size_t)524288 * 2);
    short* hd0 = (short*)take((size_t)524288 * 2);
    short* hd1 = (short*)take((size_t)524288 * 2);
    short* hBall0 = (short*)take((size_t)524288 * 2);
    float* pred_all = (float*)take((size_t)HOR * BAT * NIN * 4);
    unsigned* bars = (unsigned*)take(16384);
    short* X2t = (short*)take((size_t)TST * 131072 * 2);
    short* hBallR = X2t;   // decoder h-history overlaps dead X2 region

    // prep (re-done every call; deterministic)
    prep_fuse<<<(2048 * 512 + 255) / 256, 256, 0, stream>>>(Wc1i, Wp, Wfuse);
    prep_badd<<<8, 256, 0, stream>>>(Wc1i, bp, badd);
    prep_wp<<<(128 * 1024 + 255) / 256, 256, 0, stream>>>(Wp, W2p);
    prep_w<<<(2048 * 1280 + 255) / 256, 256, 0, stream>>>(Wih0, Whh0, W2e0, NIN, 1280);
    prep_w<<<(2048 * 2048 + 255) / 256, 256, 0, stream>>>(Wih1, Whh1, W2e1, HID, 2048);
    prep_w<<<(2048 * 2048 + 255) / 256, 256, 0, stream>>>(Wfuse, Wc1h, W2d1, HID, 2048);
    prep_w<<<(2048 * 2048 + 255) / 256, 256, 0, stream>>>(Wc2i, Wc2h, W2d2, HID, 2048);
    prep_bias<<<8, 256, 0, stream>>>(bih0, bhh0, nullptr, bias0);
    prep_bias<<<8, 256, 0, stream>>>(bih1, bhh1, nullptr, bias1);
    prep_bias<<<8, 256, 0, stream>>>(bc1i, bc1h, badd, biasd1);
    prep_bias<<<8, 256, 0, stream>>>(bc2i, bc2h, nullptr, biasd2);
    prep_x<<<(int)(((size_t)TST * BAT * NIN + 255) / 256), 256, 0, stream>>>(window, X2t);
    hipMemsetAsync(hA0, 0, (size_t)524288 * 2, stream);
    hipMemsetAsync(hB0, 0, (size_t)524288 * 2, stream);
    hipMemsetAsync(bars, 0, 16384, stream);

    hipFuncSetAttribute((const void*)persist_kernel, hipFuncAttributeMaxDynamicSharedMemorySize, 163840);
    hipFuncSetAttribute((const void*)proj_kernel, hipFuncAttributeMaxDynamicSharedMemorySize, 163840);

    persist_kernel<<<256, 512, 163840, stream>>>(
        X2t, W2e0, W2e1, W2d1, W2d2,
        hA0, hA1, hB0, hB1, hd0, hd1,
        hBall0, hBallR,
        bias0, bias1, biasd1, biasd2,
        enc_mask, dec_h_mask, dec_c_mask, bars);

    proj_kernel<<<256, 512, 102400, stream>>>(hBall0, hBallR, W2p, bp, pred_all);

    transpose_out<<<(BAT * NIN) / 64, 256, 0, stream>>>(pred_all, out);
}

// Round 11
// 1762.704 us; speedup vs baseline: 10.8658x; 1.5621x over previous
//
#include <hip/hip_runtime.h>
#include <math.h>

#define HID 512
#define BAT 512
#define NIN 128
#define TST 128
#define HOR 32
#define SBZ ((size_t)BAT * HID)

using bf16x8 = __attribute__((ext_vector_type(8))) __bf16;
using f32x4  = __attribute__((ext_vector_type(4))) float;

__device__ __forceinline__ float sigf(float x) { return 1.0f / (1.0f + __expf(-x)); }
__device__ __forceinline__ float tanhfast(float x) { return 1.0f - 2.0f / (__expf(2.0f * x) + 1.0f); }

__device__ __forceinline__ short f2bf(float x) {
    union { float f; unsigned u; } v; v.f = x;
    unsigned r = (v.u + 0x7FFFu + ((v.u >> 16) & 1u)) >> 16;
    return (short)r;
}
__device__ __forceinline__ float bf2f(short s) {
    union { unsigned u; float f; } v; v.u = ((unsigned)(unsigned short)s) << 16;
    return v.f;
}
__device__ __forceinline__ bf16x8 asbf(f32x4 v) {
    union { f32x4 f; bf16x8 b; } u; u.f = v; return u.b;
}

// Fence-free hierarchical grid barrier (r10-verified). Cross-block data moves via
// sc0sc1 loads/stores; counters are relaxed agent atomics.
__device__ __forceinline__ void gbar3(unsigned* bar, int bid, unsigned ep) {
    __syncthreads();
    if (threadIdx.x == 0) {
        unsigned* leaf = bar + ((unsigned)bid >> 3) * 32;
        unsigned* root = bar + 1024;
        unsigned* flag = bar + 1056;
        unsigned old = __hip_atomic_fetch_add(leaf, 1u, __ATOMIC_RELAXED, __HIP_MEMORY_SCOPE_AGENT);
        if (old == 8u * ep - 1u) {
            unsigned ro = __hip_atomic_fetch_add(root, 1u, __ATOMIC_RELAXED, __HIP_MEMORY_SCOPE_AGENT);
            if (ro == 32u * ep - 1u)
                __hip_atomic_store(flag, ep, __ATOMIC_RELAXED, __HIP_MEMORY_SCOPE_AGENT);
        }
        int spin = 0;
        while (__hip_atomic_load(flag, __ATOMIC_RELAXED, __HIP_MEMORY_SCOPE_AGENT) < ep) {
            __builtin_amdgcn_s_sleep(1);
            if (((++spin) & 63) == 0)
                __hip_atomic_fetch_add(flag, 0u, __ATOMIC_RELAXED, __HIP_MEMORY_SCOPE_AGENT);
        }
    }
    __syncthreads();
}

// ---------------- prep kernels ----------------

// HI-ONLY permuted weights: n' = u*4 + gate; cols [Wih_hi | Whh_hi]; row-major [2048][Kp]
__global__ __launch_bounds__(256) void prep_w(const float* __restrict__ Wih,
                                              const float* __restrict__ Whh,
                                              short* __restrict__ W2, int Kx, int Kp) {
    size_t i = (size_t)blockIdx.x * 256 + threadIdx.x;
    if (i >= (size_t)2048 * Kp) return;
    int np = (int)(i / Kp), kp = (int)(i % Kp);
    int u = np >> 2, gate = np & 3;
    int on = gate * HID + u;
    float w = (kp < Kx) ? Wih[(size_t)on * Kx + kp] : Whh[(size_t)on * HID + (kp - Kx)];
    W2[i] = f2bf(w);
}

// X2t: per-t chunks (16-row group rg = b>>4, col group cg = n>>5), 1KB chunks, lane-fragment order.
__global__ __launch_bounds__(256) void prep_x(const float* __restrict__ window,
                                              short* __restrict__ X2t) {
    size_t i = (size_t)blockIdx.x * 256 + threadIdx.x;
    if (i >= (size_t)TST * BAT * NIN) return;
    int n = (int)(i & 127);
    int b = (int)((i >> 7) & 511);
    int t = (int)(i >> 16);
    float x = window[(size_t)b * (TST * NIN) + (size_t)t * NIN + n];
    int rg = b >> 4;
    int l = (b & 15) + (((n >> 3) & 3) << 4);
    int e = n & 7;
    size_t base = (size_t)t * 65536 + ((size_t)(rg * 4 + (n >> 5)) << 9) + l * 8 + e;
    X2t[base] = f2bf(x);
}

__global__ __launch_bounds__(256) void prep_fuse(const float* __restrict__ Wc1i,
                                                 const float* __restrict__ Wp,
                                                 float* __restrict__ Wfuse) {
    size_t i = (size_t)blockIdx.x * 256 + threadIdx.x;
    if (i >= (size_t)2048 * 512) return;
    int on = (int)(i >> 9), k = (int)(i & 511);
    float s = 0.f;
    for (int n = 0; n < NIN; ++n) s += Wc1i[(size_t)on * NIN + n] * Wp[(size_t)n * HID + k];
    Wfuse[i] = s;
}

__global__ __launch_bounds__(256) void prep_badd(const float* __restrict__ Wc1i,
                                                 const float* __restrict__ bp,
                                                 float* __restrict__ badd) {
    int on = blockIdx.x * 256 + threadIdx.x;
    if (on >= 2048) return;
    float s = 0.f;
    for (int n = 0; n < NIN; ++n) s += Wc1i[(size_t)on * NIN + n] * bp[n];
    badd[on] = s;
}

__global__ __launch_bounds__(256) void prep_bias(const float* __restrict__ bih,
                                                 const float* __restrict__ bhh,
                                                 const float* __restrict__ badd,
                                                 float* __restrict__ bout) {
    int np = blockIdx.x * 256 + threadIdx.x;
    if (np >= 2048) return;
    int on = (np & 3) * HID + (np >> 2);
    float v = bih[on] + bhh[on];
    if (badd) v += badd[on];
    bout[np] = v;
}

// W2p row-major [128][512], hi only
__global__ __launch_bounds__(256) void prep_wp(const float* __restrict__ Wp,
                                               short* __restrict__ W2p) {
    int i = blockIdx.x * 256 + threadIdx.x;
    if (i >= 128 * 512) return;
    W2p[i] = f2bf(Wp[i]);
}

// ---------------- device building blocks ----------------

// resident W: 32 rows x K, k-major granules: lds[j*512 + r*16]
__device__ __forceinline__ void load_wres(char* lds, const short* Wg, int K) {
    const int tid = threadIdx.x;
    const int r = tid >> 4;
    const int cnt = K >> 7;
    const int jb = (tid & 15) * cnt;
    for (int q = 0; q < cnt; ++q) {
        int j = jb + q;
        bf16x8 v = *(const bf16x8*)(Wg + (size_t)r * K + j * 8);
        *(bf16x8*)(lds + j * 512 + r * 16) = v;
    }
}

// mask prefetch via volatile-asm loads issued BEFORE the gemm prologue (strictly older
// than counted loads -> vmcnt arithmetic stays exact).
__device__ __forceinline__ void pre_mask_asm(const float* msk, int mrow, int u0, float o[4]) {
    const int lane = threadIdx.x & 63;
    const float* p = msk + (size_t)(mrow + ((lane >> 3) << 2)) * HID + u0 + (lane & 7);
#pragma unroll
    for (int r = 0; r < 4; ++r)
        asm volatile("global_load_dword %0, %1, off" : "=v"(o[r]) : "v"(p + (size_t)r * HID));
}

// Wave-private GEMM 32(m) x 32(n') over chunked A (contiguous 1KB per load, sc0sc1),
// counted-vmcnt pipeline depth D=16; W from resident LDS. Chunks are per-16-row-group.
template<int C0, int C1>
__device__ __forceinline__ void gemm_pipeC(
    const char* wres, const short* a0t, const short* a1t,
    int mb, f32x4 acc[2][2])
{
    constexpr int NKC = C0 + C1;
    constexpr int D = 16;
    const int lane = threadIdx.x & 63;
    const int arow = lane & 15, akg = lane >> 4;
    const size_t lb = (size_t)lane << 4;
    const char* base0 = (const char*)a0t;
    const char* base1 = (const char*)a1t;
    auto cptr = [&](int kc, int fh) -> const char* {
        return (kc < C0)
            ? base0 + (((size_t)(mb * 2 + fh) * C0 + kc) << 10) + lb
            : base1 + (((size_t)(mb * 2 + fh) * C1 + (kc - C0)) << 10) + lb;
    };
    f32x4 q0[D], q1[D];
#pragma unroll
    for (int i = 0; i < D; ++i) {
        asm volatile("global_load_dwordx4 %0, %1, off sc0 sc1" : "=v"(q0[i]) : "v"(cptr(i, 0)));
        asm volatile("global_load_dwordx4 %0, %1, off sc0 sc1" : "=v"(q1[i]) : "v"(cptr(i, 1)));
    }
#pragma unroll
    for (int kc = 0; kc < NKC; ++kc) {
        const int sl = kc % D;
        asm volatile("s_waitcnt vmcnt(%2)"
                     : "+v"(q0[sl]), "+v"(q1[sl])
                     : "i"((2 * ((NKC - kc) < D ? (NKC - kc) : D)) - 2));
        const bf16x8 fa0 = asbf(q0[sl]);
        const bf16x8 fa1 = asbf(q1[sl]);
        if (kc + D < NKC) {
            asm volatile("global_load_dwordx4 %0, %1, off sc0 sc1" : "=v"(q0[sl]) : "v"(cptr(kc + D, 0)));
            asm volatile("global_load_dwordx4 %0, %1, off sc0 sc1" : "=v"(q1[sl]) : "v"(cptr(kc + D, 1)));
        }
        const char* wrow = wres + (size_t)(((kc << 2) + akg) << 9);
        const bf16x8 fb0 = *(const bf16x8*)(wrow + (arow << 4));
        const bf16x8 fb1 = *(const bf16x8*)(wrow + ((16 + arow) << 4));
        acc[0][0] = __builtin_amdgcn_mfma_f32_16x16x32_bf16(fa0, fb0, acc[0][0], 0, 0, 0);
        acc[0][1] = __builtin_amdgcn_mfma_f32_16x16x32_bf16(fa0, fb1, acc[0][1], 0, 0, 0);
        acc[1][0] = __builtin_amdgcn_mfma_f32_16x16x32_bf16(fa1, fb0, acc[1][0], 0, 0, 0);
        acc[1][1] = __builtin_amdgcn_mfma_f32_16x16x32_bf16(fa1, fb1, acc[1][1], 0, 0, 0);
    }
    asm volatile("s_waitcnt vmcnt(0)");
}

// Wave-private LSTM epilogue; c in regs; h (hi-only bf16) staged via LDS then written
// as coalesced 256B sc0sc1 dword stores (2 main + 2 aux segments per wave).
__device__ __forceinline__ void cell_epi_r(
    char* scrw, f32x4 acc[2][2], float creg[4],
    int mb, int np0, const float* bias_p,
    const float* mh4, const float* mc4, const float* ma4,
    short* h2_out, short* h2_aux)
{
    const int lane = threadIdx.x & 63;
    // 1) gates -> LDS
#pragma unroll
    for (int mi = 0; mi < 2; ++mi)
#pragma unroll
        for (int ni = 0; ni < 2; ++ni) {
            const int row = mi * 16 + ((lane >> 4) << 2);
            const int col = ni * 16 + (lane & 15);
#pragma unroll
            for (int r = 0; r < 4; ++r)
                *(float*)(scrw + (row + r) * 128 + (col << 2)) = acc[mi][ni][r];
        }
    asm volatile("s_waitcnt lgkmcnt(0)" ::: "memory");
    // 2) read own gate quads
    const int ul = lane & 7, g = lane >> 3;
    f32x4 gv[4];
#pragma unroll
    for (int r = 0; r < 4; ++r)
        gv[r] = *(const f32x4*)(scrw + ((g << 2) + r) * 128 + (ul << 4));
    asm volatile("s_waitcnt lgkmcnt(0)" ::: "memory");
    // 3) pointwise + stage bf16 into scrw[0..512) (+aux at 512)
    const float4 bs = *(const float4*)(bias_p + np0 + (ul << 2));
#pragma unroll
    for (int r = 0; r < 4; ++r) {
        const int m = (g << 2) + r;
        const int fh = m >> 4, r16 = m & 15;
        const float gi = gv[r][0] + bs.x, gf = gv[r][1] + bs.y;
        const float gg = gv[r][2] + bs.z, go = gv[r][3] + bs.w;
        const float cn = sigf(gf) * creg[r] + sigf(gi) * tanhfast(gg);
        const float h  = sigf(go) * tanhfast(cn);
        creg[r] = mc4 ? cn * mc4[r] : cn;
        const float hm = mh4 ? h * mh4[r] : h;
        const int idx2 = (r16 << 3) + ul;
        *(short*)(scrw + fh * 256 + idx2 * 2) = f2bf(hm);
        if (h2_aux)
            *(short*)(scrw + 512 + fh * 256 + idx2 * 2) = f2bf(h * ma4[r]);
    }
    // 4) coalesced sc0sc1 stores (one 256B granule per fh)
    const int u0l = np0 >> 2;
    const int c_hi = u0l >> 5, gsub = (u0l >> 3) & 3;
    unsigned vmain[2], vaux[2];
#pragma unroll
    for (int s = 0; s < 2; ++s)
        vmain[s] = *(const unsigned*)(scrw + s * 256 + (lane << 2));
    if (h2_aux)
#pragma unroll
        for (int s = 0; s < 2; ++s)
            vaux[s] = *(const unsigned*)(scrw + 512 + s * 256 + (lane << 2));
    asm volatile("s_waitcnt lgkmcnt(0)" ::: "memory");
#pragma unroll
    for (int s = 0; s < 2; ++s) {
        const unsigned* dst = (const unsigned*)(h2_out
            + ((size_t)((mb * 2 + s) * 16 + c_hi) << 9) + (gsub << 7)) + lane;
        asm volatile("global_store_dword %0, %1, off sc0 sc1" :: "v"(dst), "v"(vmain[s]));
    }
    if (h2_aux)
#pragma unroll
        for (int s = 0; s < 2; ++s) {
            const unsigned* dst = (const unsigned*)(h2_aux
                + ((size_t)((mb * 2 + s) * 16 + c_hi) << 9) + (gsub << 7)) + lane;
            asm volatile("global_store_dword %0, %1, off sc0 sc1" :: "v"(dst), "v"(vaux[s]));
        }
}

// ---------------- persistent kernel (enc + dec) ----------------

__global__ void __launch_bounds__(512, 2) persist_kernel(
    const short* X2t,
    const short* __restrict__ W0, const short* __restrict__ W1,
    const short* __restrict__ Wd1, const short* __restrict__ Wd2,
    short* hA0, short* hA1, short* hB0, short* hB1, short* hd0, short* hd1,
    short* hBall0, short* hBallR,
    const float* __restrict__ bias0, const float* __restrict__ bias1,
    const float* __restrict__ biasd1, const float* __restrict__ biasd2,
    const float* __restrict__ enc_mask, const float* __restrict__ dec_h_mask,
    const float* __restrict__ dec_c_mask, unsigned* bar)
{
    extern __shared__ __align__(16) char lds[];
    const int bid = blockIdx.x;
    const int xcd = bid & 7;                       // XCD-clustered roles
    const int half = xcd >> 2;
    const int m0 = ((xcd >> 1) & 1) * 256;
    const int np0 = (((bid >> 3) << 1) | (xcd & 1)) * 32;
    const int u0 = np0 >> 2;
    const int w = threadIdx.x >> 6;
    const int mb = (m0 >> 5) + w;
    const int mrow = m0 + (w << 5);
    char* scrw = lds + 65536 + (w << 12);
    float creg[4] = {0.f, 0.f, 0.f, 0.f};

    auto hball = [&](int s) -> short* {
        return (s == 0) ? hBall0 : hBallR + (size_t)(s - 1) * 262144;
    };

    // ---- encoder ----
    load_wres(lds, (half ? W1 : W0) + (size_t)np0 * (half ? 1024 : 640), half ? 1024 : 640);
    __syncthreads();
    unsigned ep = 0;
    for (int tt = 0; tt <= TST; ++tt) {
        if (half == 0) {
            if (tt < TST) {
                const int t = tt;
                float ma[4];
                pre_mask_asm(enc_mask + (size_t)t * SBZ, mrow, u0, ma);
                f32x4 acc[2][2];
#pragma unroll
                for (int a = 0; a < 2; ++a)
#pragma unroll
                    for (int b2 = 0; b2 < 2; ++b2) acc[a][b2] = (f32x4){0.f, 0.f, 0.f, 0.f};
                gemm_pipeC<4, 16>(lds, X2t + (size_t)t * 65536, (t & 1) ? hA1 : hA0, mb, acc);
                cell_epi_r(scrw, acc, creg, mb, np0, bias0, nullptr, nullptr, ma,
                           (t & 1) ? hA0 : hA1, (t & 1) ? hd1 : hd0);
            }
        } else {
            if (tt >= 1) {
                const int t = tt - 1;
                f32x4 acc[2][2];
#pragma unroll
                for (int a = 0; a < 2; ++a)
#pragma unroll
                    for (int b2 = 0; b2 < 2; ++b2) acc[a][b2] = (f32x4){0.f, 0.f, 0.f, 0.f};
                gemm_pipeC<16, 16>(lds, (t & 1) ? hd1 : hd0, (t & 1) ? hB1 : hB0, mb, acc);
                short* outp = (t == TST - 1) ? hball(0) : ((t & 1) ? hB0 : hB1);
                cell_epi_r(scrw, acc, creg, mb, np0, bias1, nullptr, nullptr, nullptr,
                           outp, nullptr);
            }
        }
        gbar3(bar, bid, ++ep);
    }

    // ---- decoder ----
    load_wres(lds, (half ? Wd2 : Wd1) + (size_t)np0 * 1024, 1024);
    __syncthreads();
    for (int s = 0; s < HOR - 1; ++s) {
        if (half == 0) {
            float mh[4], mc[4];
            pre_mask_asm(dec_h_mask + (size_t)s * SBZ, mrow, u0, mh);
            pre_mask_asm(dec_c_mask + (size_t)s * SBZ, mrow, u0, mc);
            f32x4 acc[2][2];
#pragma unroll
            for (int a = 0; a < 2; ++a)
#pragma unroll
                for (int b2 = 0; b2 < 2; ++b2) acc[a][b2] = (f32x4){0.f, 0.f, 0.f, 0.f};
            gemm_pipeC<16, 16>(lds, hball(s), (s & 1) ? hA1 : hA0, mb, acc);
            cell_epi_r(scrw, acc, creg, mb, np0, biasd1, mh, mc, nullptr,
                       (s & 1) ? hA0 : hA1, nullptr);
        }
        gbar3(bar, bid, ++ep);
        if (half == 1) {
            f32x4 acc[2][2];
#pragma unroll
            for (int a = 0; a < 2; ++a)
#pragma unroll
                for (int b2 = 0; b2 < 2; ++b2) acc[a][b2] = (f32x4){0.f, 0.f, 0.f, 0.f};
            gemm_pipeC<16, 16>(lds, (s & 1) ? hA0 : hA1, hball(s), mb, acc);
            cell_epi_r(scrw, acc, creg, mb, np0, biasd2, nullptr, nullptr, nullptr,
                       hball(s + 1), nullptr);
        }
        gbar3(bar, bid, ++ep);
    }
}

// ---------------- batched projection: pred_all[s][b*128+n] = hBall[s] @ Wp^T + bp ----------------

__global__ void __launch_bounds__(512, 2) proj_kernel(
    const short* hBall0, const short* hBallR, const short* __restrict__ W2p,
    const float* __restrict__ bp, float* __restrict__ pred_all)
{
    extern __shared__ __align__(16) char lds[];
    const int bid = blockIdx.x;                 // 256 = 32 s * 2 bh * 4 n0
    const int s = bid >> 3, q = bid & 7;
    const int bh = q >> 2, n0p = (q & 3) * 32;
    load_wres(lds, W2p + (size_t)n0p * 512, 512);   // 32 KB resident
    const int w = threadIdx.x >> 6, lane = threadIdx.x & 63;
    char* scrw = lds + 32768 + w * 4608;
    const int mb = bh * 8 + w;
    const short* A = (s == 0) ? hBall0 : hBallR + (size_t)(s - 1) * 262144;
    __syncthreads();
    f32x4 acc[2][2];
#pragma unroll
    for (int a = 0; a < 2; ++a)
#pragma unroll
        for (int b2 = 0; b2 < 2; ++b2) acc[a][b2] = (f32x4){0.f, 0.f, 0.f, 0.f};
    gemm_pipeC<16, 0>(lds, A, A, mb, acc);
#pragma unroll
    for (int mi = 0; mi < 2; ++mi)
#pragma unroll
        for (int ni = 0; ni < 2; ++ni) {
            const int row = mi * 16 + ((lane >> 4) << 2);
            const int col = ni * 16 + (lane & 15);
#pragma unroll
            for (int r = 0; r < 4; ++r)
                *(float*)(scrw + (row + r) * 144 + (col << 2)) = acc[mi][ni][r];
        }
    asm volatile("s_waitcnt lgkmcnt(0)" ::: "memory");
    const int rr = lane >> 1, hf = lane & 1;
    float* dst = pred_all + (size_t)s * (BAT * NIN)
               + (size_t)(bh * 256 + w * 32 + rr) * NIN + n0p + hf * 16;
#pragma unroll
    for (int t4 = 0; t4 < 4; ++t4) {
        f32x4 v = *(const f32x4*)(scrw + rr * 144 + hf * 64 + t4 * 16);
        const float4 b4 = *(const float4*)(bp + n0p + hf * 16 + t4 * 4);
        v[0] += b4.x; v[1] += b4.y; v[2] += b4.z; v[3] += b4.w;
        *(f32x4*)(dst + t4 * 4) = v;
    }
}

// out[(b*128+n)*32 + s] = pred_all[s][b*128+n]
__global__ __launch_bounds__(256) void transpose_out(const float* __restrict__ pred_all,
                                                     float* __restrict__ out) {
    __shared__ float tl[32][65];
    const int base = blockIdx.x * 64;
    const int tid = threadIdx.x;
    for (int i = tid; i < 32 * 64; i += 256) {
        int s = i >> 6, f = i & 63;
        tl[s][f] = pred_all[(size_t)s * (BAT * NIN) + base + f];
    }
    __syncthreads();
    for (int i = tid; i < 64 * 32; i += 256) {
        int f = i >> 5, s = i & 31;
        out[(size_t)(base + f) * HOR + s] = tl[s][f];
    }
}

// ---------------- host ----------------

extern "C" void kernel_launch(void* const* d_in, const int* in_sizes, int n_in,
                              void* d_out, int out_size, void* d_ws, size_t ws_size,
                              hipStream_t stream) {
    (void)in_sizes; (void)n_in; (void)out_size; (void)ws_size;
    const float* window = (const float*)d_in[0];
    const float* Wih0 = (const float*)d_in[1];
    const float* Whh0 = (const float*)d_in[2];
    const float* bih0 = (const float*)d_in[3];
    const float* bhh0 = (const float*)d_in[4];
    const float* Wih1 = (const float*)d_in[5];
    const float* Whh1 = (const float*)d_in[6];
    const float* bih1 = (const float*)d_in[7];
    const float* bhh1 = (const float*)d_in[8];
    const float* Wc1i = (const float*)d_in[9];
    const float* Wc1h = (const float*)d_in[10];
    const float* bc1i = (const float*)d_in[11];
    const float* bc1h = (const float*)d_in[12];
    const float* Wc2i = (const float*)d_in[13];
    const float* Wc2h = (const float*)d_in[14];
    const float* bc2i = (const float*)d_in[15];
    const float* bc2h = (const float*)d_in[16];
    const float* Wp   = (const float*)d_in[17];
    const float* bp   = (const float*)d_in[18];
    const float* enc_mask   = (const float*)d_in[19];
    const float* dec_h_mask = (const float*)d_in[20];
    const float* dec_c_mask = (const float*)d_in[21];
    float* out = (float*)d_out;

    char* base = (char*)d_ws;
    size_t off = 0;
    auto take = [&](size_t bytes) -> char* {
        off = (off + 255) & ~(size_t)255;
        char* r = base + off; off += bytes; return r;
    };
    short* W2e0 = (short*)take((size_t)2048 * 640 * 2);
    short* W2e1 = (short*)take((size_t)2048 * 1024 * 2);
    short* W2d1 = (short*)take((size_t)2048 * 1024 * 2);   // fused [Wfuse|Wc1h] hi
    short* W2d2 = (short*)take((size_t)2048 * 1024 * 2);
    short* W2p  = (short*)take((size_t)128 * 512 * 2);
    float* Wfuse = (float*)take((size_t)2048 * 512 * 4);
    float* badd  = (float*)take((size_t)2048 * 4);
    float* bias0 = (float*)take((size_t)2048 * 4);
    float* bias1 = (float*)take((size_t)2048 * 4);
    float* biasd1 = (float*)take((size_t)2048 * 4);
    float* biasd2 = (float*)take((size_t)2048 * 4);
    short* hA0 = (short*)take((size_t)262144 * 2);
    short* hA1 = (short*)take((size_t)262144 * 2);
    short* hB0 = (short*)take((size_t)262144 * 2);
    short* hB1 = (short*)take((size_t)262144 * 2);
    short* hd0 = (short*)take((size_t)262144 * 2);
    short* hd1 = (short*)take((size_t)262144 * 2);
    short* hBall0 = (short*)take((size_t)262144 * 2);
    float* pred_all = (float*)take((size_t)HOR * BAT * NIN * 4);
    unsigned* bars = (unsigned*)take(16384);
    short* X2t = (short*)take((size_t)TST * 65536 * 2);
    short* hBallR = X2t;   // decoder h-history overlaps dead X2 region (15.5MB <= 16MB)

    // prep (re-done every call; deterministic)
    prep_fuse<<<(2048 * 512 + 255) / 256, 256, 0, stream>>>(Wc1i, Wp, Wfuse);
    prep_badd<<<8, 256, 0, stream>>>(Wc1i, bp, badd);
    prep_wp<<<(128 * 512 + 255) / 256, 256, 0, stream>>>(Wp, W2p);
    prep_w<<<(2048 * 640 + 255) / 256, 256, 0, stream>>>(Wih0, Whh0, W2e0, NIN, 640);
    prep_w<<<(2048 * 1024 + 255) / 256, 256, 0, stream>>>(Wih1, Whh1, W2e1, HID, 1024);
    prep_w<<<(2048 * 1024 + 255) / 256, 256, 0, stream>>>(Wfuse, Wc1h, W2d1, HID, 1024);
    prep_w<<<(2048 * 1024 + 255) / 256, 256, 0, stream>>>(Wc2i, Wc2h, W2d2, HID, 1024);
    prep_bias<<<8, 256, 0, stream>>>(bih0, bhh0, nullptr, bias0);
    prep_bias<<<8, 256, 0, stream>>>(bih1, bhh1, nullptr, bias1);
    prep_bias<<<8, 256, 0, stream>>>(bc1i, bc1h, badd, biasd1);
    prep_bias<<<8, 256, 0, stream>>>(bc2i, bc2h, nullptr, biasd2);
    prep_x<<<(int)(((size_t)TST * BAT * NIN + 255) / 256), 256, 0, stream>>>(window, X2t);
    hipMemsetAsync(hA0, 0, (size_t)262144 * 2, stream);
    hipMemsetAsync(hB0, 0, (size_t)262144 * 2, stream);
    hipMemsetAsync(bars, 0, 16384, stream);

    hipFuncSetAttribute((const void*)persist_kernel, hipFuncAttributeMaxDynamicSharedMemorySize, 98304);
    hipFuncSetAttribute((const void*)proj_kernel, hipFuncAttributeMaxDynamicSharedMemorySize, 69632);

    persist_kernel<<<256, 512, 98304, stream>>>(
        X2t, W2e0, W2e1, W2d1, W2d2,
        hA0, hA1, hB0, hB1, hd0, hd1,
        hBall0, hBallR,
        bias0, bias1, biasd1, biasd2,
        enc_mask, dec_h_mask, dec_c_mask, bars);

    proj_kernel<<<256, 512, 69632, stream>>>(hBall0, hBallR, W2p, bp, pred_all);

    transpose_out<<<(BAT * NIN) / 64, 256, 0, stream>>>(pred_all, out);
}